// Round 12
// baseline (180.553 us; speedup 1.0000x reference)
//
#include <hip/hip_runtime.h>
#include <hip/hip_bf16.h>
#include <math.h>

// Problem constants (fixed by setup_inputs)
#define B_  2
#define NH  4
#define HH  64
#define WW  64
#define KD  32
#define L_  4096            // HH*WW
#define BN_ 8               // B_*NH
#define LOG2E 1.4426950408889634f
#define KSCALE (0.17677669529663687f * 1.4426950408889634f)  // log2e/sqrt(32)
#define FIXED_M 10.0f   // log2-domain fixed softmax shift (shift-invariant =>
                        // exact); scores max ~3, p=2^(s-10) f16-safe to s>26.

typedef float    f32x4  __attribute__((ext_vector_type(4), may_alias));
typedef _Float16 half8  __attribute__((ext_vector_type(8), may_alias));
typedef _Float16 half4  __attribute__((ext_vector_type(4), may_alias));
typedef __fp16   fp16x2 __attribute__((ext_vector_type(2)));
typedef unsigned uint4v __attribute__((ext_vector_type(4)));

__device__ __forceinline__ float fexp2(float x) {
#if __has_builtin(__builtin_amdgcn_exp2f)
    return __builtin_amdgcn_exp2f(x);
#else
    return __expf(x * 0.69314718056f);
#endif
}

__device__ __forceinline__ unsigned pack2u(float a, float b) {
    fp16x2 t = __builtin_amdgcn_cvt_pkrtz(a, b);   // v_cvt_pkrtz_f16_f32
    union { fp16x2 i; unsigned o; } u;
    u.i = t;
    return u.o;
}

// ---------------------------------------------------------------------------
// Kernel A: qkv = x @ w_qkv (M=8192,K=128,N=384). f16 outputs: q_h/k_h
// [bn][l][32] (k pre-scaled by log2e/sqrt32), vt_h [bn][32][lperm]:
// V transposed AND key-permuted within each 32-key group so the attention
// PV A-operand is a contiguous half8 load and the QK C-layout IS the PV
// B-operand layout with zero data movement.
// ---------------------------------------------------------------------------
__global__ __launch_bounds__(256) void qkv_gemm(const float* __restrict__ x,
                                                const float* __restrict__ w,
                                                _Float16* __restrict__ q_h,
                                                _Float16* __restrict__ k_h,
                                                _Float16* __restrict__ vt_h) {
    __shared__ float As[64][68];
    __shared__ float Bs[64][68];
    const int mt = blockIdx.x % 128;
    const int nt = blockIdx.x / 128;
    const int m0 = mt * 64, n0 = nt * 64;
    const int tid = threadIdx.x;
    const int ti = tid / 16, tj = tid % 16;
    float acc[4][4] = {};

    for (int k0 = 0; k0 < 128; k0 += 64) {
        #pragma unroll
        for (int i = 0; i < 16; i++) {
            int e = i * 256 + tid;
            As[e >> 6][e & 63] = x[(m0 + (e >> 6)) * 128 + k0 + (e & 63)];
        }
        #pragma unroll
        for (int i = 0; i < 16; i++) {
            int e = i * 256 + tid;
            Bs[e >> 6][e & 63] = w[(k0 + (e >> 6)) * 384 + n0 + (e & 63)];
        }
        __syncthreads();
        #pragma unroll 8
        for (int kk = 0; kk < 64; kk++) {
            float av[4];
            #pragma unroll
            for (int r = 0; r < 4; r++) av[r] = As[ti * 4 + r][kk];
            const float4 b4 = *(const float4*)&Bs[kk][tj * 4];
            const float bv[4] = {b4.x, b4.y, b4.z, b4.w};
            #pragma unroll
            for (int r = 0; r < 4; r++)
                #pragma unroll
                for (int c = 0; c < 4; c++)
                    acc[r][c] = fmaf(av[r], bv[c], acc[r][c]);
        }
        __syncthreads();
    }

    const int which = n0 >> 7;                 // 0=q, 1=k, 2=v
    const int nc = n0 & 127;
    const int b = m0 >> 12;
    if (which < 2) {
        _Float16* dst = (which == 0) ? q_h : k_h;
        const float mult = (which == 1) ? KSCALE : 1.0f;
        #pragma unroll
        for (int r = 0; r < 4; r++) {
            const int l = (m0 & 4095) + ti * 4 + r;
            #pragma unroll
            for (int c = 0; c < 4; c++) {
                const int col = nc + tj * 4 + c;
                const int bn = b * NH + (col >> 5);
                dst[((size_t)bn * L_ + l) * 32 + (col & 31)] = (_Float16)(acc[r][c] * mult);
            }
        }
    } else {
        // LDS transpose, then key-permuted coalesced stores
        #pragma unroll
        for (int r = 0; r < 4; r++)
            #pragma unroll
            for (int c = 0; c < 4; c++)
                As[tj * 4 + c][ti * 4 + r] = acc[r][c];
        __syncthreads();
        const int c2 = tid >> 2;           // local col (channel) 0..63
        const int lg = tid & 3;            // l-group
        const int gcol = nc + c2;
        const int bn = b * NH + (gcol >> 5);
        const int d = gcol & 31;
        _Float16* dst = vt_h + ((size_t)bn * 32 + d) * L_ + (m0 & 4095)
                      + (lg >> 1) * 32 + (lg & 1) * 4;
        #pragma unroll
        for (int g = 0; g < 4; g++) {
            half4 o;
            o[0] = (_Float16)As[c2][lg * 16 + g * 4 + 0];
            o[1] = (_Float16)As[c2][lg * 16 + g * 4 + 1];
            o[2] = (_Float16)As[c2][lg * 16 + g * 4 + 2];
            o[3] = (_Float16)As[c2][lg * 16 + g * 4 + 3];
            *(half4*)(dst + g * 8) = o;
        }
    }
}

// ---------------------------------------------------------------------------
// Kernel B: qh bias table via MFMA (Toeplitz rows), log2 domain, f16.
//   qh: per (bn,h1): C[w1][h2] = Q·Eh[h2-h1+63] -> qh_abs[bn][h1][w1][h2]
// grid 512 = bn*64 + pos, 64 threads (1 wave, 16 mfma).
// ---------------------------------------------------------------------------
__global__ __launch_bounds__(64) void bias_mfma(const _Float16* __restrict__ q_h,
                                                const float* __restrict__ emb_h,
                                                float* __restrict__ qh_abs) {
    const int bi = blockIdx.x;
    const int bn = bi >> 6;
    const int pos = bi & 63;             // h1
    const int lane = threadIdx.x;
    const int l16 = lane & 15;
    const int quad = lane >> 4;
    const _Float16* Q = q_h + (size_t)bn * L_ * 32;

    half8 Aq[4];
    #pragma unroll
    for (int w1t = 0; w1t < 4; w1t++)
        Aq[w1t] = *(const half8*)(Q + ((size_t)pos * 64 + w1t * 16 + l16) * 32 + quad * 8);
    #pragma unroll
    for (int h2t = 0; h2t < 4; h2t++) {
        const int j = h2t * 16 + l16 - pos + 63;        // 0..126
        const float* eh = emb_h + j * 32 + quad * 8;
        half8 Bf;
        #pragma unroll
        for (int e = 0; e < 8; e++) Bf[e] = (_Float16)(eh[e] * LOG2E);
        #pragma unroll
        for (int w1t = 0; w1t < 4; w1t++) {
            f32x4 C = {0.f, 0.f, 0.f, 0.f};
            C = __builtin_amdgcn_mfma_f32_16x16x32_f16(Aq[w1t], Bf, C, 0, 0, 0);
            #pragma unroll
            for (int r = 0; r < 4; r++)
                qh_abs[(((size_t)bn * 64 + pos) * 64 + w1t * 16 + quad * 4 + r) * 64
                       + h2t * 16 + l16] = C[r];
        }
    }
}

// ---------------------------------------------------------------------------
// Kernel C: transposed MFMA flash attention, fixed-m softmax, key-permuted V.
// R12: grid 1024 = (bn, w1, q-half) -> 4 blocks/CU (was 2, grid-limited at
// 42% occupancy). Block = 8 waves = 2 q-groups x 4 KEY-QUARTERS (16 iters
// per wave). Same ~460cy dependency chain per iter, but 8 waves/SIMD of
// independent chains to fill it (VGPR=48 fits 8 waves/SIMD). 2 q-waves per
// quarter share K/V addresses (L1 hits). 4-way key merge in-block.
// ---------------------------------------------------------------------------
__global__ __launch_bounds__(512, 4) void attn_mfma(
    const _Float16* __restrict__ q_h,    // [bn][l][32]
    const _Float16* __restrict__ k_h,    // [bn][l][32] pre-scaled
    const _Float16* __restrict__ vt_h,   // [bn][32][lperm]
    const float* __restrict__ qh_abs,    // [bn][h1][w1][h2], log2 dom
    const float* __restrict__ emb_w,     // [127][32] f32
    float* __restrict__ out)
{
    __shared__ __align__(16) char smem[17920];   // qh_s 8.4KB | merge 17.9KB

    const int bi   = blockIdx.x;
    const int bn   = bi & 7;             // XCD swizzle
    const int w1   = (bi >> 3) & 63;
    const int qhf  = bi >> 9;            // q-half 0/1
    const int tid  = threadIdx.x;
    const int wv   = tid >> 6;           // 0..7
    const int qwv  = wv & 1;             // q-group 0/1
    const int kq   = wv >> 1;            // key quarter 0..3
    const int lane = tid & 63;
    const int l16  = lane & 15;
    const int quad = lane >> 4;
    const int q0   = qhf * 32 + qwv * 16;

    float* qh_s = (float*)smem;          // [h2][q32] stride 33

    // ---- stage qh slice (32 h1 x 64 h2 f32), transposed ----
    {
        const int h1  = tid >> 4;            // local q 0..31
        const int h2b = (tid & 15) * 4;
        const float* src = qh_abs
            + (((size_t)(bn * 64 + qhf * 32 + h1) * 64) + w1) * 64 + h2b;
        const float4 v = *(const float4*)src;
        qh_s[(h2b + 0) * 33 + h1] = v.x;
        qh_s[(h2b + 1) * 33 + h1] = v.y;
        qh_s[(h2b + 2) * 33 + h1] = v.z;
        qh_s[(h2b + 3) * 33 + h1] = v.w;
    }

    // ---- Q fragment (B-operand): Q[q=l16][d=quad*8..+8) ----
    const half8 aq = *(const half8*)(q_h +
        (((size_t)bn * L_ + (q0 + l16) * 64 + w1) * 32 + quad * 8));

    // ---- qw^T C-init via in-block Toeplitz MFMA; Ew converted inline ----
    f32x4 qwT[4];
    #pragma unroll
    for (int sub = 0; sub < 4; sub++) {
        const float* ew = emb_w + (size_t)(sub * 16 + l16 - w1 + 63) * 32 + quad * 8;
        const float4 e0 = *(const float4*)ew;
        const float4 e1 = *(const float4*)(ew + 4);
        union { uint4v u; half8 h; } ua;
        ua.u[0] = pack2u(e0.x * LOG2E, e0.y * LOG2E);
        ua.u[1] = pack2u(e0.z * LOG2E, e0.w * LOG2E);
        ua.u[2] = pack2u(e1.x * LOG2E, e1.y * LOG2E);
        ua.u[3] = pack2u(e1.z * LOG2E, e1.w * LOG2E);
        f32x4 z = {0.f, 0.f, 0.f, 0.f};
        qwT[sub] = __builtin_amdgcn_mfma_f32_16x16x32_f16(ua.h, aq, z, 0, 0, 0);
    }

    const _Float16* Kbase = k_h  + (size_t)bn * L_ * 32;
    const _Float16* Vbase = vt_h + (size_t)bn * 32 * L_;

    const int kt0 = kq * 16, ktend = kt0 + 16;

    half8 kf[4];
    #pragma unroll
    for (int sub = 0; sub < 4; sub++)
        kf[sub] = *(const half8*)(Kbase + (size_t)(kt0 * 64 + sub * 16 + l16) * 32 + quad * 8);

    __syncthreads();    // qh_s ready

    f32x4 O0 = {0.f, 0.f, 0.f, 0.f}, O1 = {0.f, 0.f, 0.f, 0.f};
    float l0 = 0.f, l1 = 0.f;

    #pragma unroll 2
    for (int kt = kt0; kt < ktend; kt++) {
        // ---- qh from LDS (per-lane q scalar; broadcast over quads) ----
        const float qh_cur = qh_s[kt * 33 + qwv * 16 + l16];

        // ---- V loads (coalesced half8; shared addresses across q-waves) ----
        const half8 va00 = *(const half8*)(Vbase + (size_t)l16 * L_        + kt * 64      + quad * 8);
        const half8 va01 = *(const half8*)(Vbase + (size_t)l16 * L_        + kt * 64 + 32 + quad * 8);
        const half8 va10 = *(const half8*)(Vbase + (size_t)(16 + l16) * L_ + kt * 64      + quad * 8);
        const half8 va11 = *(const half8*)(Vbase + (size_t)(16 + l16) * L_ + kt * 64 + 32 + quad * 8);

        // ---- QK^T transposed: S^T[key][q], bias qw as C-init ----
        f32x4 S0 = __builtin_amdgcn_mfma_f32_16x16x32_f16(kf[0], aq, qwT[0], 0, 0, 0);
        f32x4 S1 = __builtin_amdgcn_mfma_f32_16x16x32_f16(kf[1], aq, qwT[1], 0, 0, 0);
        f32x4 S2 = __builtin_amdgcn_mfma_f32_16x16x32_f16(kf[2], aq, qwT[2], 0, 0, 0);
        f32x4 S3 = __builtin_amdgcn_mfma_f32_16x16x32_f16(kf[3], aq, qwT[3], 0, 0, 0);

        // ---- prefetch next K tile, unconditional ----
        #pragma unroll
        for (int sub = 0; sub < 4; sub++)
            kf[sub] = *(const half8*)(Kbase + (size_t)((kt + 1) * 64 + sub * 16 + l16) * 32 + quad * 8);

        const float mqv = FIXED_M - qh_cur;

        // ---- fixed-m softmax: p = 2^(S + qh - 10); u32-concat pack ----
        union { uint4v u; half8 h; } pb0, pb1;
        {
            const float a0 = fexp2(S0[0] - mqv), a1 = fexp2(S0[1] - mqv);
            const float a2 = fexp2(S0[2] - mqv), a3 = fexp2(S0[3] - mqv);
            const float b0 = fexp2(S1[0] - mqv), b1 = fexp2(S1[1] - mqv);
            const float b2 = fexp2(S1[2] - mqv), b3 = fexp2(S1[3] - mqv);
            l0 += ((a0 + a1) + (a2 + a3)) + ((b0 + b1) + (b2 + b3));
            pb0.u[0] = pack2u(a0, a1); pb0.u[1] = pack2u(a2, a3);
            pb0.u[2] = pack2u(b0, b1); pb0.u[3] = pack2u(b2, b3);
        }
        {
            const float a0 = fexp2(S2[0] - mqv), a1 = fexp2(S2[1] - mqv);
            const float a2 = fexp2(S2[2] - mqv), a3 = fexp2(S2[3] - mqv);
            const float b0 = fexp2(S3[0] - mqv), b1 = fexp2(S3[1] - mqv);
            const float b2 = fexp2(S3[2] - mqv), b3 = fexp2(S3[3] - mqv);
            l1 += ((a0 + a1) + (a2 + a3)) + ((b0 + b1) + (b2 + b3));
            pb1.u[0] = pack2u(a0, a1); pb1.u[1] = pack2u(a2, a3);
            pb1.u[2] = pack2u(b0, b1); pb1.u[3] = pack2u(b2, b3);
        }

        // ---- PV: O^T[d][q] += Vt_perm · P^T (4x 16x16x32) ----
        O0 = __builtin_amdgcn_mfma_f32_16x16x32_f16(va00, pb0.h, O0, 0, 0, 0);
        O0 = __builtin_amdgcn_mfma_f32_16x16x32_f16(va01, pb1.h, O0, 0, 0, 0);
        O1 = __builtin_amdgcn_mfma_f32_16x16x32_f16(va10, pb0.h, O1, 0, 0, 0);
        O1 = __builtin_amdgcn_mfma_f32_16x16x32_f16(va11, pb1.h, O1, 0, 0, 0);
    }

    // ---- reduce l over quads (per-lane q = l16) ----
    float l = l0 + l1;
    l += __shfl_xor(l, 16);
    l += __shfl_xor(l, 32);

    // ---- merge overlay (qh_s dead after barrier) ----
    __syncthreads();
    float (*mO)[32][17] = (float(*)[32][17])smem;     // [wave][d][q16]
    float* mL = (float*)(smem + 17408);               // [wave][16]
    #pragma unroll
    for (int r = 0; r < 4; r++) {
        mO[wv][quad * 4 + r][l16]      = O0[r];
        mO[wv][16 + quad * 4 + r][l16] = O1[r];
    }
    if (quad == 0) mL[wv * 16 + l16] = l;
    __syncthreads();

    // epilogue: q = tid>>4 (0..31 local), dd = tid&15 (d and d+16)
    const int q  = tid >> 4;
    const int dd = tid & 15;
    const int qg = q >> 4, ql = q & 15;     // qg = q-group
    float denom = 0.f, oa = 0.f, ob = 0.f;
    #pragma unroll
    for (int s = 0; s < 4; s++) {           // key quarters
        const int w = s * 2 + qg;
        denom += mL[w * 16 + ql];
        oa += mO[w][dd][ql];
        ob += mO[w][dd + 16][ql];
    }
    const float inv = 1.0f / denom;
    const int head = bn & 3, bb = bn >> 2;
    const size_t oi = (((size_t)bb * 64 + qhf * 32 + q) * 64 + w1) * 128 + head * 32;
    out[oi + dd]      = oa * inv;
    out[oi + dd + 16] = ob * inv;
}

// ---------------------------------------------------------------------------
extern "C" void kernel_launch(void* const* d_in, const int* in_sizes, int n_in,
                              void* d_out, int out_size, void* d_ws, size_t ws_size,
                              hipStream_t stream) {
    const float* x     = (const float*)d_in[0];   // [2,64,64,128]
    const float* w_qkv = (const float*)d_in[1];   // [128,384]
    const float* emb_h = (const float*)d_in[2];   // [127,32]
    const float* emb_w = (const float*)d_in[3];   // [127,32]
    float* out = (float*)d_out;

    // workspace: qh_abs 2M f32 | q_h/k_h/vt_h 1M half each (vt_h doubles as
    // the guard for the unconditional last-iteration K prefetch)
    float* qh_abs = (float*)d_ws;
    _Float16* q_h  = (_Float16*)(qh_abs + (size_t)BN_ * 64 * L_);
    _Float16* k_h  = q_h + (size_t)BN_ * L_ * KD;
    _Float16* vt_h = k_h + (size_t)BN_ * L_ * KD;

    qkv_gemm<<<768, 256, 0, stream>>>(x, w_qkv, q_h, k_h, vt_h);
    bias_mfma<<<512, 64, 0, stream>>>(q_h, emb_h, qh_abs);
    attn_mfma<<<1024, 512, 0, stream>>>(q_h, k_h, vt_h, qh_abs, emb_w, out);
}

// Round 13
// 133.279 us; speedup vs baseline: 1.3547x; 1.3547x over previous
//
#include <hip/hip_runtime.h>
#include <hip/hip_bf16.h>
#include <math.h>

// Problem constants (fixed by setup_inputs)
#define B_  2
#define NH  4
#define HH  64
#define WW  64
#define KD  32
#define L_  4096            // HH*WW
#define BN_ 8               // B_*NH
#define LOG2E 1.4426950408889634f
#define KSCALE (0.17677669529663687f * 1.4426950408889634f)  // log2e/sqrt(32)
#define FIXED_M 10.0f   // log2-domain fixed softmax shift (shift-invariant =>
                        // exact); scores max ~3, p=2^(s-10) f16-safe to s>26.

typedef float    f32x4  __attribute__((ext_vector_type(4), may_alias));
typedef _Float16 half8  __attribute__((ext_vector_type(8), may_alias));
typedef _Float16 half4  __attribute__((ext_vector_type(4), may_alias));
typedef __fp16   fp16x2 __attribute__((ext_vector_type(2)));
typedef unsigned uint4v __attribute__((ext_vector_type(4)));

__device__ __forceinline__ float fexp2(float x) {
#if __has_builtin(__builtin_amdgcn_exp2f)
    return __builtin_amdgcn_exp2f(x);
#else
    return __expf(x * 0.69314718056f);
#endif
}

__device__ __forceinline__ unsigned pack2u(float a, float b) {
    fp16x2 t = __builtin_amdgcn_cvt_pkrtz(a, b);   // v_cvt_pkrtz_f16_f32
    union { fp16x2 i; unsigned o; } u;
    u.i = t;
    return u.o;
}

// ---------------------------------------------------------------------------
// Kernel A: qkv = x @ w_qkv (M=8192,K=128,N=384). f16 outputs: q_h/k_h
// [bn][l][32] (k pre-scaled by log2e/sqrt32), and TILE-PACKED V:
// vt_h[bn][kt][ (y*2+x)*512 + lane*8 + j ] where (y = keyhalf, x = dhalf,
// lane = quad*16 + (d&15), key permutation k = ((p&15)>>2)*8 + ((p>>4)&1)*4
// + (p&3), quad = k>>3, j = k&7). This makes the attention PV A-operand a
// single lane-contiguous 1KB-segment load (same shape as the K loads) --
// eliminating the 16-way 8KB-stride row gather that R8-R12 paid 4x per iter.
// ---------------------------------------------------------------------------
__global__ __launch_bounds__(256) void qkv_gemm(const float* __restrict__ x,
                                                const float* __restrict__ w,
                                                _Float16* __restrict__ q_h,
                                                _Float16* __restrict__ k_h,
                                                _Float16* __restrict__ vt_h) {
    __shared__ float As[64][68];
    __shared__ float Bs[64][68];
    const int mt = blockIdx.x % 128;
    const int nt = blockIdx.x / 128;
    const int m0 = mt * 64, n0 = nt * 64;
    const int tid = threadIdx.x;
    const int ti = tid / 16, tj = tid % 16;
    float acc[4][4] = {};

    for (int k0 = 0; k0 < 128; k0 += 64) {
        #pragma unroll
        for (int i = 0; i < 16; i++) {
            int e = i * 256 + tid;
            As[e >> 6][e & 63] = x[(m0 + (e >> 6)) * 128 + k0 + (e & 63)];
        }
        #pragma unroll
        for (int i = 0; i < 16; i++) {
            int e = i * 256 + tid;
            Bs[e >> 6][e & 63] = w[(k0 + (e >> 6)) * 384 + n0 + (e & 63)];
        }
        __syncthreads();
        #pragma unroll 8
        for (int kk = 0; kk < 64; kk++) {
            float av[4];
            #pragma unroll
            for (int r = 0; r < 4; r++) av[r] = As[ti * 4 + r][kk];
            const float4 b4 = *(const float4*)&Bs[kk][tj * 4];
            const float bv[4] = {b4.x, b4.y, b4.z, b4.w};
            #pragma unroll
            for (int r = 0; r < 4; r++)
                #pragma unroll
                for (int c = 0; c < 4; c++)
                    acc[r][c] = fmaf(av[r], bv[c], acc[r][c]);
        }
        __syncthreads();
    }

    const int which = n0 >> 7;                 // 0=q, 1=k, 2=v
    const int nc = n0 & 127;
    const int b = m0 >> 12;
    if (which < 2) {
        _Float16* dst = (which == 0) ? q_h : k_h;
        const float mult = (which == 1) ? KSCALE : 1.0f;
        #pragma unroll
        for (int r = 0; r < 4; r++) {
            const int l = (m0 & 4095) + ti * 4 + r;
            #pragma unroll
            for (int c = 0; c < 4; c++) {
                const int col = nc + tj * 4 + c;
                const int bn = b * NH + (col >> 5);
                dst[((size_t)bn * L_ + l) * 32 + (col & 31)] = (_Float16)(acc[r][c] * mult);
            }
        }
    } else {
        // Write acc into an LDS image in FINAL tile-packed layout (pad +1/16
        // float -> <=4-way write conflicts), then linear coalesced stores.
        float* img = &As[0][0];              // 4352 floats >= 4350 needed
        #pragma unroll
        for (int r = 0; r < 4; r++)
            #pragma unroll
            for (int c = 0; c < 4; c++) {
                const int p    = ti * 4 + r;          // local key 0..63
                const int chan = tj * 4 + c;          // 0..63 (2 heads x 32d)
                const int h    = chan >> 5;
                const int d    = chan & 31;
                const int y    = p >> 5;
                const int p32  = p & 31;
                const int quad = (p32 >> 2) & 3;
                const int j    = ((p32 >> 4) & 1) * 4 + (p32 & 3);
                const int fidx = h * 2048 + (y * 2 + (d >> 4)) * 512
                               + (quad * 16 + (d & 15)) * 8 + j;
                img[fidx + (fidx >> 4)] = acc[r][c];
            }
        __syncthreads();
        const int ktg = (m0 & 4095) >> 6;     // key tile 0..63
        #pragma unroll
        for (int h = 0; h < 2; h++) {
            const int head = (nc >> 5) + h;          // global head 0..3
            const int bn = b * NH + head;
            const int fbase = h * 2048 + tid * 8;
            const int sbase = fbase + (fbase >> 4);
            half8 o;
            #pragma unroll
            for (int e = 0; e < 8; e++) o[e] = (_Float16)img[sbase + e];
            *(half8*)(vt_h + (size_t)bn * 131072 + ktg * 2048 + tid * 8) = o;
        }
    }
}

// ---------------------------------------------------------------------------
// Kernel B: qh bias table via MFMA (Toeplitz rows), log2 domain, f16.
//   qh: per (bn,h1): C[w1][h2] = Q·Eh[h2-h1+63] -> qh_abs[bn][h1][w1][h2]
// grid 512 = bn*64 + pos, 64 threads (1 wave, 16 mfma).
// ---------------------------------------------------------------------------
__global__ __launch_bounds__(64) void bias_mfma(const _Float16* __restrict__ q_h,
                                                const float* __restrict__ emb_h,
                                                float* __restrict__ qh_abs) {
    const int bi = blockIdx.x;
    const int bn = bi >> 6;
    const int pos = bi & 63;             // h1
    const int lane = threadIdx.x;
    const int l16 = lane & 15;
    const int quad = lane >> 4;
    const _Float16* Q = q_h + (size_t)bn * L_ * 32;

    half8 Aq[4];
    #pragma unroll
    for (int w1t = 0; w1t < 4; w1t++)
        Aq[w1t] = *(const half8*)(Q + ((size_t)pos * 64 + w1t * 16 + l16) * 32 + quad * 8);
    #pragma unroll
    for (int h2t = 0; h2t < 4; h2t++) {
        const int j = h2t * 16 + l16 - pos + 63;        // 0..126
        const float* eh = emb_h + j * 32 + quad * 8;
        half8 Bf;
        #pragma unroll
        for (int e = 0; e < 8; e++) Bf[e] = (_Float16)(eh[e] * LOG2E);
        #pragma unroll
        for (int w1t = 0; w1t < 4; w1t++) {
            f32x4 C = {0.f, 0.f, 0.f, 0.f};
            C = __builtin_amdgcn_mfma_f32_16x16x32_f16(Aq[w1t], Bf, C, 0, 0, 0);
            #pragma unroll
            for (int r = 0; r < 4; r++)
                qh_abs[(((size_t)bn * 64 + pos) * 64 + w1t * 16 + quad * 4 + r) * 64
                       + h2t * 16 + l16] = C[r];
        }
    }
}

// ---------------------------------------------------------------------------
// Kernel C: transposed MFMA flash attention, fixed-m softmax, TILE-PACKED V.
// Structure = R11 (its best): block (bn,w1), 8 waves = 4 q-groups x 2 key
// halves; 4 q-waves per half share K/V addresses (L1 hits); qh staged in LDS;
// qw bias via in-block Toeplitz MFMA. R13 change: V loads are now single
// 1KB-segment lane-contiguous half8s (tb + subblock*512 + lane*8) -- the
// 16-way row gather is gone.
// ---------------------------------------------------------------------------
__global__ __launch_bounds__(512, 4) void attn_mfma(
    const _Float16* __restrict__ q_h,    // [bn][l][32]
    const _Float16* __restrict__ k_h,    // [bn][l][32] pre-scaled
    const _Float16* __restrict__ vt_h,   // [bn][kt][2048] tile-packed
    const float* __restrict__ qh_abs,    // [bn][h1][w1][h2], log2 dom
    const float* __restrict__ emb_w,     // [127][32] f32
    float* __restrict__ out)
{
    __shared__ __align__(16) char smem[17920];   // qh_s (16.6KB) | merge

    const int bi   = blockIdx.x;
    const int bn   = bi & 7;             // XCD swizzle
    const int w1   = bi >> 3;            // 0..63
    const int tid  = threadIdx.x;
    const int wv   = tid >> 6;           // 0..7
    const int qwv  = wv & 3;             // q-group
    const int kh   = wv >> 2;            // key half
    const int lane = tid & 63;
    const int l16  = lane & 15;
    const int quad = lane >> 4;
    const int q0   = qwv * 16;

    float* qh_s = (float*)smem;          // [h2][h1] pad 65

    // ---- stage qh slice (64x64 f32), transposed ----
    {
        const int h1 = tid >> 3;
        const int h2b = (tid & 7) * 8;
        const float* src = qh_abs + (((size_t)(bn * 64 + h1) * 64) + w1) * 64 + h2b;
        const float4 v0 = *(const float4*)src;
        const float4 v1 = *(const float4*)(src + 4);
        qh_s[(h2b + 0) * 65 + h1] = v0.x;
        qh_s[(h2b + 1) * 65 + h1] = v0.y;
        qh_s[(h2b + 2) * 65 + h1] = v0.z;
        qh_s[(h2b + 3) * 65 + h1] = v0.w;
        qh_s[(h2b + 4) * 65 + h1] = v1.x;
        qh_s[(h2b + 5) * 65 + h1] = v1.y;
        qh_s[(h2b + 6) * 65 + h1] = v1.z;
        qh_s[(h2b + 7) * 65 + h1] = v1.w;
    }

    // ---- Q fragment (B-operand): Q[q=l16][d=quad*8..+8) ----
    const half8 aq = *(const half8*)(q_h +
        (((size_t)bn * L_ + (q0 + l16) * 64 + w1) * 32 + quad * 8));

    // ---- qw^T C-init via in-block Toeplitz MFMA; Ew converted inline ----
    f32x4 qwT[4];
    #pragma unroll
    for (int sub = 0; sub < 4; sub++) {
        const float* ew = emb_w + (size_t)(sub * 16 + l16 - w1 + 63) * 32 + quad * 8;
        const float4 e0 = *(const float4*)ew;
        const float4 e1 = *(const float4*)(ew + 4);
        union { uint4v u; half8 h; } ua;
        ua.u[0] = pack2u(e0.x * LOG2E, e0.y * LOG2E);
        ua.u[1] = pack2u(e0.z * LOG2E, e0.w * LOG2E);
        ua.u[2] = pack2u(e1.x * LOG2E, e1.y * LOG2E);
        ua.u[3] = pack2u(e1.z * LOG2E, e1.w * LOG2E);
        f32x4 z = {0.f, 0.f, 0.f, 0.f};
        qwT[sub] = __builtin_amdgcn_mfma_f32_16x16x32_f16(ua.h, aq, z, 0, 0, 0);
    }

    const _Float16* Kbase = k_h  + (size_t)bn * L_ * 32;
    const _Float16* Vtile = vt_h + (size_t)bn * 131072;
    const int lo = lane * 8;

    const int kt0 = kh * 32, ktend = kt0 + 32;

    half8 kf[4];
    #pragma unroll
    for (int sub = 0; sub < 4; sub++)
        kf[sub] = *(const half8*)(Kbase + (size_t)(kt0 * 64 + sub * 16 + l16) * 32 + quad * 8);

    __syncthreads();    // qh_s ready

    f32x4 O0 = {0.f, 0.f, 0.f, 0.f}, O1 = {0.f, 0.f, 0.f, 0.f};
    float l0 = 0.f, l1 = 0.f;

    #pragma unroll 4
    for (int kt = kt0; kt < ktend; kt++) {
        // ---- qh from LDS (per-lane q scalar; broadcast over quads) ----
        const float qh_cur = qh_s[kt * 65 + q0 + l16];

        // ---- V loads: single 1KB-segment lane-contiguous half8 each ----
        const _Float16* tb = Vtile + kt * 2048;
        const half8 va00 = *(const half8*)(tb + lo);           // d0-15, k0-31
        const half8 va10 = *(const half8*)(tb + 512 + lo);     // d16-31, k0-31
        const half8 va01 = *(const half8*)(tb + 1024 + lo);    // d0-15, k32-63
        const half8 va11 = *(const half8*)(tb + 1536 + lo);    // d16-31, k32-63

        // ---- QK^T transposed: S^T[key][q], bias qw as C-init ----
        f32x4 S0 = __builtin_amdgcn_mfma_f32_16x16x32_f16(kf[0], aq, qwT[0], 0, 0, 0);
        f32x4 S1 = __builtin_amdgcn_mfma_f32_16x16x32_f16(kf[1], aq, qwT[1], 0, 0, 0);
        f32x4 S2 = __builtin_amdgcn_mfma_f32_16x16x32_f16(kf[2], aq, qwT[2], 0, 0, 0);
        f32x4 S3 = __builtin_amdgcn_mfma_f32_16x16x32_f16(kf[3], aq, qwT[3], 0, 0, 0);

        // ---- prefetch next K tile, unconditional ----
        #pragma unroll
        for (int sub = 0; sub < 4; sub++)
            kf[sub] = *(const half8*)(Kbase + (size_t)((kt + 1) * 64 + sub * 16 + l16) * 32 + quad * 8);

        const float mqv = FIXED_M - qh_cur;

        // ---- fixed-m softmax: p = 2^(S + qh - 10); u32-concat pack ----
        union { uint4v u; half8 h; } pb0, pb1;
        {
            const float a0 = fexp2(S0[0] - mqv), a1 = fexp2(S0[1] - mqv);
            const float a2 = fexp2(S0[2] - mqv), a3 = fexp2(S0[3] - mqv);
            const float b0 = fexp2(S1[0] - mqv), b1 = fexp2(S1[1] - mqv);
            const float b2 = fexp2(S1[2] - mqv), b3 = fexp2(S1[3] - mqv);
            l0 += ((a0 + a1) + (a2 + a3)) + ((b0 + b1) + (b2 + b3));
            pb0.u[0] = pack2u(a0, a1); pb0.u[1] = pack2u(a2, a3);
            pb0.u[2] = pack2u(b0, b1); pb0.u[3] = pack2u(b2, b3);
        }
        {
            const float a0 = fexp2(S2[0] - mqv), a1 = fexp2(S2[1] - mqv);
            const float a2 = fexp2(S2[2] - mqv), a3 = fexp2(S2[3] - mqv);
            const float b0 = fexp2(S3[0] - mqv), b1 = fexp2(S3[1] - mqv);
            const float b2 = fexp2(S3[2] - mqv), b3 = fexp2(S3[3] - mqv);
            l1 += ((a0 + a1) + (a2 + a3)) + ((b0 + b1) + (b2 + b3));
            pb1.u[0] = pack2u(a0, a1); pb1.u[1] = pack2u(a2, a3);
            pb1.u[2] = pack2u(b0, b1); pb1.u[3] = pack2u(b2, b3);
        }

        // ---- PV: O^T[d][q] += V_tile · P^T (4x 16x16x32) ----
        O0 = __builtin_amdgcn_mfma_f32_16x16x32_f16(va00, pb0.h, O0, 0, 0, 0);
        O0 = __builtin_amdgcn_mfma_f32_16x16x32_f16(va01, pb1.h, O0, 0, 0, 0);
        O1 = __builtin_amdgcn_mfma_f32_16x16x32_f16(va10, pb0.h, O1, 0, 0, 0);
        O1 = __builtin_amdgcn_mfma_f32_16x16x32_f16(va11, pb1.h, O1, 0, 0, 0);
    }

    // ---- reduce l over quads (per-lane q = l16) ----
    float l = l0 + l1;
    l += __shfl_xor(l, 16);
    l += __shfl_xor(l, 32);

    // ---- merge overlay (qh_s dead after barrier) ----
    __syncthreads();
    float (*mO)[32][17] = (float(*)[32][17])smem;     // [wave][d][q16]
    float* mL = (float*)(smem + 17408);               // [wave][16]
    #pragma unroll
    for (int r = 0; r < 4; r++) {
        mO[wv][quad * 4 + r][l16]      = O0[r];
        mO[wv][16 + quad * 4 + r][l16] = O1[r];
    }
    if (quad == 0) mL[wv * 16 + l16] = l;
    __syncthreads();

    // thread t: q = t>>3 (0..63), dg = t&7 (4 channels) -> coalesced float4
    const int q  = tid >> 3;
    const int dg = tid & 7;
    const int qg = q >> 4, ql = q & 15;
    const float denom = mL[qg * 16 + ql] + mL[(qg + 4) * 16 + ql];
    const float inv = 1.0f / denom;
    float4 o;
    o.x = (mO[qg][dg * 4 + 0][ql] + mO[qg + 4][dg * 4 + 0][ql]) * inv;
    o.y = (mO[qg][dg * 4 + 1][ql] + mO[qg + 4][dg * 4 + 1][ql]) * inv;
    o.z = (mO[qg][dg * 4 + 2][ql] + mO[qg + 4][dg * 4 + 2][ql]) * inv;
    o.w = (mO[qg][dg * 4 + 3][ql] + mO[qg + 4][dg * 4 + 3][ql]) * inv;
    const int head = bn & 3, bb = bn >> 2;
    *(float4*)&out[(((size_t)bb * 64 + q) * 64 + w1) * 128 + head * 32 + dg * 4] = o;
}

// ---------------------------------------------------------------------------
extern "C" void kernel_launch(void* const* d_in, const int* in_sizes, int n_in,
                              void* d_out, int out_size, void* d_ws, size_t ws_size,
                              hipStream_t stream) {
    const float* x     = (const float*)d_in[0];   // [2,64,64,128]
    const float* w_qkv = (const float*)d_in[1];   // [128,384]
    const float* emb_h = (const float*)d_in[2];   // [127,32]
    const float* emb_w = (const float*)d_in[3];   // [127,32]
    float* out = (float*)d_out;

    // workspace: qh_abs 2M f32 | q_h/k_h 1M half each | vt_h 1M half tiled
    // (vt_h also guards the unconditional last-iteration K prefetch)
    float* qh_abs = (float*)d_ws;
    _Float16* q_h  = (_Float16*)(qh_abs + (size_t)BN_ * 64 * L_);
    _Float16* k_h  = q_h + (size_t)BN_ * L_ * KD;
    _Float16* vt_h = k_h + (size_t)BN_ * L_ * KD;

    qkv_gemm<<<768, 256, 0, stream>>>(x, w_qkv, q_h, k_h, vt_h);
    bias_mfma<<<512, 64, 0, stream>>>(q_h, emb_h, qh_abs);
    attn_mfma<<<512, 512, 0, stream>>>(q_h, k_h, vt_h, qh_abs, emb_w, out);
}

// Round 14
// 132.607 us; speedup vs baseline: 1.3616x; 1.0051x over previous
//
#include <hip/hip_runtime.h>
#include <hip/hip_bf16.h>
#include <math.h>

// Problem constants (fixed by setup_inputs)
#define B_  2
#define NH  4
#define HH  64
#define WW  64
#define KD  32
#define L_  4096            // HH*WW
#define BN_ 8               // B_*NH
#define LOG2E 1.4426950408889634f
#define KSCALE (0.17677669529663687f * 1.4426950408889634f)  // log2e/sqrt(32)
#define FIXED_M 10.0f   // log2-domain fixed softmax shift (shift-invariant =>
                        // exact); scores max ~3, p=2^(s-10) f16-safe to s>26.

typedef float    f32x4  __attribute__((ext_vector_type(4), may_alias));
typedef _Float16 half8  __attribute__((ext_vector_type(8), may_alias));
typedef _Float16 half4  __attribute__((ext_vector_type(4), may_alias));
typedef __fp16   fp16x2 __attribute__((ext_vector_type(2)));
typedef unsigned uint4v __attribute__((ext_vector_type(4)));

__device__ __forceinline__ float fexp2(float x) {
#if __has_builtin(__builtin_amdgcn_exp2f)
    return __builtin_amdgcn_exp2f(x);
#else
    return __expf(x * 0.69314718056f);
#endif
}

__device__ __forceinline__ unsigned pack2u(float a, float b) {
    fp16x2 t = __builtin_amdgcn_cvt_pkrtz(a, b);   // v_cvt_pkrtz_f16_f32
    union { fp16x2 i; unsigned o; } u;
    u.i = t;
    return u.o;
}

// ---------------------------------------------------------------------------
// Kernel A: qkv = x @ w_qkv (M=8192,K=128,N=384) -- NOW f16 MFMA (was fp32
// VALU). K=128 fits one LDS staging pass (no k-loop): x-tile 64x128 f16,
// w-tile transposed [n][k] f16 so B-frags are contiguous half8. 4 waves x
// 16 MFMA (16x16x32). Outputs: q_h/k_h [bn][l][32] (k pre-scaled), and
// TILE-PACKED V via LDS image (R13 layout: attention PV A-operand = single
// lane-contiguous 1KB-segment half8).
// ---------------------------------------------------------------------------
__global__ __launch_bounds__(256) void qkv_gemm(const float* __restrict__ x,
                                                const float* __restrict__ w,
                                                _Float16* __restrict__ q_h,
                                                _Float16* __restrict__ k_h,
                                                _Float16* __restrict__ vt_h) {
    __shared__ __align__(16) char smem[34816];
    _Float16* xs  = (_Float16*)smem;            // [64][136] (17408 B)
    _Float16* wsT = (_Float16*)(smem + 17408);  // [64][136] transposed w

    const int mt = blockIdx.x % 128;
    const int nt = blockIdx.x / 128;
    const int m0 = mt * 64, n0 = nt * 64;
    const int tid = threadIdx.x;
    const int wv = tid >> 6, lane = tid & 63;
    const int l16 = lane & 15, quad = lane >> 4;

    // ---- stage x tile 64x128 fp32 -> f16 ----
    #pragma unroll
    for (int i = 0; i < 8; i++) {
        const int idx = i * 256 + tid;          // 2048 float4 slots
        const int row = idx >> 5, c4 = (idx & 31) * 4;
        const float4 v = *(const float4*)&x[(size_t)(m0 + row) * 128 + c4];
        half4 h;
        h[0] = (_Float16)v.x; h[1] = (_Float16)v.y;
        h[2] = (_Float16)v.z; h[3] = (_Float16)v.w;
        *(half4*)&xs[row * 136 + c4] = h;
    }
    // ---- stage w tile 128x64 fp32 -> f16 transposed [n][k] ----
    #pragma unroll
    for (int i = 0; i < 8; i++) {
        const int idx = i * 256 + tid;          // 2048 float4 slots
        const int k = idx >> 4, c4 = (idx & 15) * 4;
        const float4 v = *(const float4*)&w[(size_t)k * 384 + n0 + c4];
        wsT[(c4 + 0) * 136 + k] = (_Float16)v.x;
        wsT[(c4 + 1) * 136 + k] = (_Float16)v.y;
        wsT[(c4 + 2) * 136 + k] = (_Float16)v.z;
        wsT[(c4 + 3) * 136 + k] = (_Float16)v.w;
    }
    __syncthreads();

    // ---- compute: wave wv owns rows [wv*16,+16) x all 64 cols ----
    f32x4 acc[4] = {{0.f,0.f,0.f,0.f},{0.f,0.f,0.f,0.f},
                    {0.f,0.f,0.f,0.f},{0.f,0.f,0.f,0.f}};
    half8 af[4];
    #pragma unroll
    for (int kc = 0; kc < 4; kc++)
        af[kc] = *(const half8*)&xs[(wv * 16 + l16) * 136 + kc * 32 + quad * 8];
    #pragma unroll
    for (int ns = 0; ns < 4; ns++)
        #pragma unroll
        for (int kc = 0; kc < 4; kc++) {
            const half8 bf = *(const half8*)&wsT[(ns * 16 + l16) * 136 + kc * 32 + quad * 8];
            acc[ns] = __builtin_amdgcn_mfma_f32_16x16x32_f16(af[kc], bf, acc[ns], 0, 0, 0);
        }

    const int which = n0 >> 7;                 // 0=q, 1=k, 2=v
    const int nc = n0 & 127;
    const int b = m0 >> 12;
    if (which < 2) {
        _Float16* dst = (which == 0) ? q_h : k_h;
        const float mult = (which == 1) ? KSCALE : 1.0f;
        #pragma unroll
        for (int ns = 0; ns < 4; ns++) {
            const int col = nc + ns * 16 + l16;
            const int bn = b * NH + (col >> 5);
            const int d = col & 31;
            #pragma unroll
            for (int r = 0; r < 4; r++) {
                const int l = (m0 & 4095) + wv * 16 + quad * 4 + r;
                dst[((size_t)bn * L_ + l) * 32 + d] = (_Float16)(acc[ns][r] * mult);
            }
        }
    } else {
        // tile-packed V: write acc into LDS image (final layout, +1/16 pad),
        // then linear coalesced half8 stores.
        __syncthreads();                        // xs dead -> overlay img
        float* img = (float*)smem;              // 4352 floats
        #pragma unroll
        for (int ns = 0; ns < 4; ns++) {
            const int chan = ns * 16 + l16;     // 0..63 (2 heads x 32d)
            const int h = chan >> 5, d = chan & 31;
            #pragma unroll
            for (int r = 0; r < 4; r++) {
                const int p = wv * 16 + quad * 4 + r;     // local key 0..63
                const int y = p >> 5, p32 = p & 31;
                const int q4 = (p32 >> 2) & 3;
                const int j = ((p32 >> 4) & 1) * 4 + (p32 & 3);
                const int fidx = h * 2048 + (y * 2 + (d >> 4)) * 512
                               + (q4 * 16 + (d & 15)) * 8 + j;
                img[fidx + (fidx >> 4)] = acc[ns][r];
            }
        }
        __syncthreads();
        const int ktg = (m0 & 4095) >> 6;       // key tile 0..63
        #pragma unroll
        for (int h = 0; h < 2; h++) {
            const int head = (nc >> 5) + h;
            const int bn = b * NH + head;
            const int fbase = h * 2048 + tid * 8;
            const int sbase = fbase + (fbase >> 4);
            half8 o;
            #pragma unroll
            for (int e = 0; e < 8; e++) o[e] = (_Float16)img[sbase + e];
            *(half8*)(vt_h + (size_t)bn * 131072 + ktg * 2048 + tid * 8) = o;
        }
    }
}

// ---------------------------------------------------------------------------
// Kernel B: qh bias table via MFMA (Toeplitz rows), log2 domain, f16.
//   qh: per (bn,h1): C[w1][h2] = Q·Eh[h2-h1+63] -> qh_abs[bn][h1][w1][h2]
// R14: grid 1024 = (bn, pos, w1-half) -- 2x the waves (latency-bound gather
// kernel at 2 waves/CU), each wave does 2 w1t groups (8 mfma).
// ---------------------------------------------------------------------------
__global__ __launch_bounds__(64) void bias_mfma(const _Float16* __restrict__ q_h,
                                                const float* __restrict__ emb_h,
                                                float* __restrict__ qh_abs) {
    const int bi = blockIdx.x;
    const int bn = bi >> 7;
    const int pos = (bi >> 1) & 63;      // h1
    const int half = bi & 1;
    const int lane = threadIdx.x;
    const int l16 = lane & 15;
    const int quad = lane >> 4;
    const _Float16* Q = q_h + (size_t)bn * L_ * 32;

    half8 Aq[2];
    #pragma unroll
    for (int wi = 0; wi < 2; wi++) {
        const int w1t = half * 2 + wi;
        Aq[wi] = *(const half8*)(Q + ((size_t)pos * 64 + w1t * 16 + l16) * 32 + quad * 8);
    }
    #pragma unroll
    for (int h2t = 0; h2t < 4; h2t++) {
        const int j = h2t * 16 + l16 - pos + 63;        // 0..126
        const float* eh = emb_h + j * 32 + quad * 8;
        half8 Bf;
        #pragma unroll
        for (int e = 0; e < 8; e++) Bf[e] = (_Float16)(eh[e] * LOG2E);
        #pragma unroll
        for (int wi = 0; wi < 2; wi++) {
            const int w1t = half * 2 + wi;
            f32x4 C = {0.f, 0.f, 0.f, 0.f};
            C = __builtin_amdgcn_mfma_f32_16x16x32_f16(Aq[wi], Bf, C, 0, 0, 0);
            #pragma unroll
            for (int r = 0; r < 4; r++)
                qh_abs[(((size_t)bn * 64 + pos) * 64 + w1t * 16 + quad * 4 + r) * 64
                       + h2t * 16 + l16] = C[r];
        }
    }
}

// ---------------------------------------------------------------------------
// Kernel C: transposed MFMA flash attention, fixed-m softmax, tile-packed V.
// R14: grid 1024 = (bn, w1, q-half) -> 2x resident blocks (retrying R12's
// split now that the V-gather TA bottleneck is gone; VGPR=44 allows 8
// waves/SIMD). Block = 8 waves = 2 q-groups x 4 key-quarters (16 iters).
// V loads: single 1KB-segment lane-contiguous half8 (R13).
// ---------------------------------------------------------------------------
__global__ __launch_bounds__(512, 4) void attn_mfma(
    const _Float16* __restrict__ q_h,    // [bn][l][32]
    const _Float16* __restrict__ k_h,    // [bn][l][32] pre-scaled
    const _Float16* __restrict__ vt_h,   // [bn][kt][2048] tile-packed
    const float* __restrict__ qh_abs,    // [bn][h1][w1][h2], log2 dom
    const float* __restrict__ emb_w,     // [127][32] f32
    float* __restrict__ out)
{
    __shared__ __align__(16) char smem[17920];   // qh_s 8.4KB | merge 17.9KB

    const int bi   = blockIdx.x;
    const int bn   = bi & 7;             // XCD swizzle
    const int w1   = (bi >> 3) & 63;
    const int qhf  = bi >> 9;            // q-half 0/1
    const int tid  = threadIdx.x;
    const int wv   = tid >> 6;           // 0..7
    const int qwv  = wv & 1;             // q-group 0/1
    const int kq   = wv >> 1;            // key quarter 0..3
    const int lane = tid & 63;
    const int l16  = lane & 15;
    const int quad = lane >> 4;
    const int q0   = qhf * 32 + qwv * 16;

    float* qh_s = (float*)smem;          // [h2][q32] stride 33

    // ---- stage qh slice (32 h1 x 64 h2 f32), transposed ----
    {
        const int h1  = tid >> 4;            // local q 0..31
        const int h2b = (tid & 15) * 4;
        const float* src = qh_abs
            + (((size_t)(bn * 64 + qhf * 32 + h1) * 64) + w1) * 64 + h2b;
        const float4 v = *(const float4*)src;
        qh_s[(h2b + 0) * 33 + h1] = v.x;
        qh_s[(h2b + 1) * 33 + h1] = v.y;
        qh_s[(h2b + 2) * 33 + h1] = v.z;
        qh_s[(h2b + 3) * 33 + h1] = v.w;
    }

    // ---- Q fragment (B-operand): Q[q=l16][d=quad*8..+8) ----
    const half8 aq = *(const half8*)(q_h +
        (((size_t)bn * L_ + (q0 + l16) * 64 + w1) * 32 + quad * 8));

    // ---- qw^T C-init via in-block Toeplitz MFMA; Ew converted inline ----
    f32x4 qwT[4];
    #pragma unroll
    for (int sub = 0; sub < 4; sub++) {
        const float* ew = emb_w + (size_t)(sub * 16 + l16 - w1 + 63) * 32 + quad * 8;
        const float4 e0 = *(const float4*)ew;
        const float4 e1 = *(const float4*)(ew + 4);
        union { uint4v u; half8 h; } ua;
        ua.u[0] = pack2u(e0.x * LOG2E, e0.y * LOG2E);
        ua.u[1] = pack2u(e0.z * LOG2E, e0.w * LOG2E);
        ua.u[2] = pack2u(e1.x * LOG2E, e1.y * LOG2E);
        ua.u[3] = pack2u(e1.z * LOG2E, e1.w * LOG2E);
        f32x4 z = {0.f, 0.f, 0.f, 0.f};
        qwT[sub] = __builtin_amdgcn_mfma_f32_16x16x32_f16(ua.h, aq, z, 0, 0, 0);
    }

    const _Float16* Kbase = k_h  + (size_t)bn * L_ * 32;
    const _Float16* Vtile = vt_h + (size_t)bn * 131072;
    const int lo = lane * 8;

    const int kt0 = kq * 16, ktend = kt0 + 16;

    half8 kf[4];
    #pragma unroll
    for (int sub = 0; sub < 4; sub++)
        kf[sub] = *(const half8*)(Kbase + (size_t)(kt0 * 64 + sub * 16 + l16) * 32 + quad * 8);

    __syncthreads();    // qh_s ready

    f32x4 O0 = {0.f, 0.f, 0.f, 0.f}, O1 = {0.f, 0.f, 0.f, 0.f};
    float l0 = 0.f, l1 = 0.f;

    #pragma unroll 4
    for (int kt = kt0; kt < ktend; kt++) {
        // ---- qh from LDS (per-lane q scalar; broadcast over quads) ----
        const float qh_cur = qh_s[kt * 33 + qwv * 16 + l16];

        // ---- V loads: single 1KB-segment lane-contiguous half8 each ----
        const _Float16* tb = Vtile + kt * 2048;
        const half8 va00 = *(const half8*)(tb + lo);           // d0-15, k0-31
        const half8 va10 = *(const half8*)(tb + 512 + lo);     // d16-31, k0-31
        const half8 va01 = *(const half8*)(tb + 1024 + lo);    // d0-15, k32-63
        const half8 va11 = *(const half8*)(tb + 1536 + lo);    // d16-31, k32-63

        // ---- QK^T transposed: S^T[key][q], bias qw as C-init ----
        f32x4 S0 = __builtin_amdgcn_mfma_f32_16x16x32_f16(kf[0], aq, qwT[0], 0, 0, 0);
        f32x4 S1 = __builtin_amdgcn_mfma_f32_16x16x32_f16(kf[1], aq, qwT[1], 0, 0, 0);
        f32x4 S2 = __builtin_amdgcn_mfma_f32_16x16x32_f16(kf[2], aq, qwT[2], 0, 0, 0);
        f32x4 S3 = __builtin_amdgcn_mfma_f32_16x16x32_f16(kf[3], aq, qwT[3], 0, 0, 0);

        // ---- prefetch next K tile, unconditional ----
        #pragma unroll
        for (int sub = 0; sub < 4; sub++)
            kf[sub] = *(const half8*)(Kbase + (size_t)((kt + 1) * 64 + sub * 16 + l16) * 32 + quad * 8);

        const float mqv = FIXED_M - qh_cur;

        // ---- fixed-m softmax: p = 2^(S + qh - 10); u32-concat pack ----
        union { uint4v u; half8 h; } pb0, pb1;
        {
            const float a0 = fexp2(S0[0] - mqv), a1 = fexp2(S0[1] - mqv);
            const float a2 = fexp2(S0[2] - mqv), a3 = fexp2(S0[3] - mqv);
            const float b0 = fexp2(S1[0] - mqv), b1 = fexp2(S1[1] - mqv);
            const float b2 = fexp2(S1[2] - mqv), b3 = fexp2(S1[3] - mqv);
            l0 += ((a0 + a1) + (a2 + a3)) + ((b0 + b1) + (b2 + b3));
            pb0.u[0] = pack2u(a0, a1); pb0.u[1] = pack2u(a2, a3);
            pb0.u[2] = pack2u(b0, b1); pb0.u[3] = pack2u(b2, b3);
        }
        {
            const float a0 = fexp2(S2[0] - mqv), a1 = fexp2(S2[1] - mqv);
            const float a2 = fexp2(S2[2] - mqv), a3 = fexp2(S2[3] - mqv);
            const float b0 = fexp2(S3[0] - mqv), b1 = fexp2(S3[1] - mqv);
            const float b2 = fexp2(S3[2] - mqv), b3 = fexp2(S3[3] - mqv);
            l1 += ((a0 + a1) + (a2 + a3)) + ((b0 + b1) + (b2 + b3));
            pb1.u[0] = pack2u(a0, a1); pb1.u[1] = pack2u(a2, a3);
            pb1.u[2] = pack2u(b0, b1); pb1.u[3] = pack2u(b2, b3);
        }

        // ---- PV: O^T[d][q] += V_tile · P^T (4x 16x16x32) ----
        O0 = __builtin_amdgcn_mfma_f32_16x16x32_f16(va00, pb0.h, O0, 0, 0, 0);
        O0 = __builtin_amdgcn_mfma_f32_16x16x32_f16(va01, pb1.h, O0, 0, 0, 0);
        O1 = __builtin_amdgcn_mfma_f32_16x16x32_f16(va10, pb0.h, O1, 0, 0, 0);
        O1 = __builtin_amdgcn_mfma_f32_16x16x32_f16(va11, pb1.h, O1, 0, 0, 0);
    }

    // ---- reduce l over quads (per-lane q = l16) ----
    float l = l0 + l1;
    l += __shfl_xor(l, 16);
    l += __shfl_xor(l, 32);

    // ---- merge overlay (qh_s dead after barrier) ----
    __syncthreads();
    float (*mO)[32][17] = (float(*)[32][17])smem;     // [wave][d][q16]
    float* mL = (float*)(smem + 17408);               // [wave][16]
    #pragma unroll
    for (int r = 0; r < 4; r++) {
        mO[wv][quad * 4 + r][l16]      = O0[r];
        mO[wv][16 + quad * 4 + r][l16] = O1[r];
    }
    if (quad == 0) mL[wv * 16 + l16] = l;
    __syncthreads();

    // epilogue: q = tid>>4 (0..31 local), dd = tid&15 (d and d+16)
    const int q  = tid >> 4;
    const int dd = tid & 15;
    const int qg = q >> 4, ql = q & 15;     // qg = q-group
    float denom = 0.f, oa = 0.f, ob = 0.f;
    #pragma unroll
    for (int s = 0; s < 4; s++) {           // key quarters
        const int w = s * 2 + qg;
        denom += mL[w * 16 + ql];
        oa += mO[w][dd][ql];
        ob += mO[w][dd + 16][ql];
    }
    const float inv = 1.0f / denom;
    const int head = bn & 3, bb = bn >> 2;
    const size_t oi = (((size_t)bb * 64 + qhf * 32 + q) * 64 + w1) * 128 + head * 32;
    out[oi + dd]      = oa * inv;
    out[oi + dd + 16] = ob * inv;
}

// ---------------------------------------------------------------------------
extern "C" void kernel_launch(void* const* d_in, const int* in_sizes, int n_in,
                              void* d_out, int out_size, void* d_ws, size_t ws_size,
                              hipStream_t stream) {
    const float* x     = (const float*)d_in[0];   // [2,64,64,128]
    const float* w_qkv = (const float*)d_in[1];   // [128,384]
    const float* emb_h = (const float*)d_in[2];   // [127,32]
    const float* emb_w = (const float*)d_in[3];   // [127,32]
    float* out = (float*)d_out;

    // workspace: qh_abs 2M f32 | q_h/k_h 1M half each | vt_h 1M half tiled
    // (vt_h also guards the unconditional last-iteration K prefetch)
    float* qh_abs = (float*)d_ws;
    _Float16* q_h  = (_Float16*)(qh_abs + (size_t)BN_ * 64 * L_);
    _Float16* k_h  = q_h + (size_t)BN_ * L_ * KD;
    _Float16* vt_h = k_h + (size_t)BN_ * L_ * KD;

    qkv_gemm<<<768, 256, 0, stream>>>(x, w_qkv, q_h, k_h, vt_h);
    bias_mfma<<<1024, 64, 0, stream>>>(q_h, emb_h, qh_abs);
    attn_mfma<<<1024, 512, 0, stream>>>(q_h, k_h, vt_h, qh_abs, emb_w, out);
}

// Round 15
// 130.292 us; speedup vs baseline: 1.3858x; 1.0178x over previous
//
#include <hip/hip_runtime.h>
#include <hip/hip_bf16.h>
#include <math.h>

// Problem constants (fixed by setup_inputs)
#define B_  2
#define NH  4
#define HH  64
#define WW  64
#define KD  32
#define L_  4096            // HH*WW
#define BN_ 8               // B_*NH
#define LOG2E 1.4426950408889634f
#define KSCALE (0.17677669529663687f * 1.4426950408889634f)  // log2e/sqrt(32)
#define FIXED_M 10.0f   // log2-domain fixed softmax shift (shift-invariant =>
                        // exact); scores max ~3, p=2^(s-10) f16-safe to s>26.

typedef float    f32x4  __attribute__((ext_vector_type(4), may_alias));
typedef _Float16 half8  __attribute__((ext_vector_type(8), may_alias));
typedef _Float16 half4  __attribute__((ext_vector_type(4), may_alias));
typedef __fp16   fp16x2 __attribute__((ext_vector_type(2)));
typedef unsigned uint4v __attribute__((ext_vector_type(4)));

__device__ __forceinline__ float fexp2(float x) {
#if __has_builtin(__builtin_amdgcn_exp2f)
    return __builtin_amdgcn_exp2f(x);
#else
    return __expf(x * 0.69314718056f);
#endif
}

__device__ __forceinline__ unsigned pack2u(float a, float b) {
    fp16x2 t = __builtin_amdgcn_cvt_pkrtz(a, b);   // v_cvt_pkrtz_f16_f32
    union { fp16x2 i; unsigned o; } u;
    u.i = t;
    return u.o;
}

// ---------------------------------------------------------------------------
// Kernel A: qkv = x @ w_qkv (M=8192,K=128,N=384), f16 MFMA, single LDS pass
// (K=128). Outputs: q_h/k_h [bn][l][32] (k pre-scaled by log2e/sqrt32), and
// TILE-PACKED V (R13 layout): attention PV A-operand = single lane-contiguous
// 1KB-segment half8.
// ---------------------------------------------------------------------------
__global__ __launch_bounds__(256) void qkv_gemm(const float* __restrict__ x,
                                                const float* __restrict__ w,
                                                _Float16* __restrict__ q_h,
                                                _Float16* __restrict__ k_h,
                                                _Float16* __restrict__ vt_h) {
    __shared__ __align__(16) char smem[34816];
    _Float16* xs  = (_Float16*)smem;            // [64][136]
    _Float16* wsT = (_Float16*)(smem + 17408);  // [64][136] transposed w

    const int mt = blockIdx.x % 128;
    const int nt = blockIdx.x / 128;
    const int m0 = mt * 64, n0 = nt * 64;
    const int tid = threadIdx.x;
    const int wv = tid >> 6, lane = tid & 63;
    const int l16 = lane & 15, quad = lane >> 4;

    #pragma unroll
    for (int i = 0; i < 8; i++) {
        const int idx = i * 256 + tid;
        const int row = idx >> 5, c4 = (idx & 31) * 4;
        const float4 v = *(const float4*)&x[(size_t)(m0 + row) * 128 + c4];
        half4 h;
        h[0] = (_Float16)v.x; h[1] = (_Float16)v.y;
        h[2] = (_Float16)v.z; h[3] = (_Float16)v.w;
        *(half4*)&xs[row * 136 + c4] = h;
    }
    #pragma unroll
    for (int i = 0; i < 8; i++) {
        const int idx = i * 256 + tid;
        const int k = idx >> 4, c4 = (idx & 15) * 4;
        const float4 v = *(const float4*)&w[(size_t)k * 384 + n0 + c4];
        wsT[(c4 + 0) * 136 + k] = (_Float16)v.x;
        wsT[(c4 + 1) * 136 + k] = (_Float16)v.y;
        wsT[(c4 + 2) * 136 + k] = (_Float16)v.z;
        wsT[(c4 + 3) * 136 + k] = (_Float16)v.w;
    }
    __syncthreads();

    f32x4 acc[4] = {{0.f,0.f,0.f,0.f},{0.f,0.f,0.f,0.f},
                    {0.f,0.f,0.f,0.f},{0.f,0.f,0.f,0.f}};
    half8 af[4];
    #pragma unroll
    for (int kc = 0; kc < 4; kc++)
        af[kc] = *(const half8*)&xs[(wv * 16 + l16) * 136 + kc * 32 + quad * 8];
    #pragma unroll
    for (int ns = 0; ns < 4; ns++)
        #pragma unroll
        for (int kc = 0; kc < 4; kc++) {
            const half8 bf = *(const half8*)&wsT[(ns * 16 + l16) * 136 + kc * 32 + quad * 8];
            acc[ns] = __builtin_amdgcn_mfma_f32_16x16x32_f16(af[kc], bf, acc[ns], 0, 0, 0);
        }

    const int which = n0 >> 7;                 // 0=q, 1=k, 2=v
    const int nc = n0 & 127;
    const int b = m0 >> 12;
    if (which < 2) {
        _Float16* dst = (which == 0) ? q_h : k_h;
        const float mult = (which == 1) ? KSCALE : 1.0f;
        #pragma unroll
        for (int ns = 0; ns < 4; ns++) {
            const int col = nc + ns * 16 + l16;
            const int bn = b * NH + (col >> 5);
            const int d = col & 31;
            #pragma unroll
            for (int r = 0; r < 4; r++) {
                const int l = (m0 & 4095) + wv * 16 + quad * 4 + r;
                dst[((size_t)bn * L_ + l) * 32 + d] = (_Float16)(acc[ns][r] * mult);
            }
        }
    } else {
        __syncthreads();                        // xs dead -> overlay img
        float* img = (float*)smem;
        #pragma unroll
        for (int ns = 0; ns < 4; ns++) {
            const int chan = ns * 16 + l16;
            const int h = chan >> 5, d = chan & 31;
            #pragma unroll
            for (int r = 0; r < 4; r++) {
                const int p = wv * 16 + quad * 4 + r;
                const int y = p >> 5, p32 = p & 31;
                const int q4 = (p32 >> 2) & 3;
                const int j = ((p32 >> 4) & 1) * 4 + (p32 & 3);
                const int fidx = h * 2048 + (y * 2 + (d >> 4)) * 512
                               + (q4 * 16 + (d & 15)) * 8 + j;
                img[fidx + (fidx >> 4)] = acc[ns][r];
            }
        }
        __syncthreads();
        const int ktg = (m0 & 4095) >> 6;
        #pragma unroll
        for (int h = 0; h < 2; h++) {
            const int head = (nc >> 5) + h;
            const int bn = b * NH + head;
            const int fbase = h * 2048 + tid * 8;
            const int sbase = fbase + (fbase >> 4);
            half8 o;
            #pragma unroll
            for (int e = 0; e < 8; e++) o[e] = (_Float16)img[sbase + e];
            *(half8*)(vt_h + (size_t)bn * 131072 + ktg * 2048 + tid * 8) = o;
        }
    }
}

// ---------------------------------------------------------------------------
// Kernel B: transposed MFMA flash attention; fixed-m softmax; tile-packed V;
// BOTH biases fused in-block (no bias kernel, no tables):
//   qw^T: Toeplitz MFMA vs emb_w (C-init, with -FIXED_M folded in)
//   qh:   R[h1][j] = Q[h1,w1]·Eh[j] via 32 MFMAs (4/wave, A-frag = aq) into
//         LDS; loop reads qh = R[h1][kt-h1+63] (conflict-free, quad-bcast).
// 2-TILE PIPELINE SKEW: iter t issues QK(t+1) MFMAs, then exp/packs S(t)
// (results a full iteration old -> no MFMA-latency stall), then PV(t).
// Block (bn,w1), 8 waves = 4 q-groups x 2 key-halves (R13 shape - grid
// splits beyond 512 proven non-helpful in R12/R14).
// ---------------------------------------------------------------------------
__global__ __launch_bounds__(512, 4) void attn_mfma(
    const _Float16* __restrict__ q_h,    // [bn][l][32]
    const _Float16* __restrict__ k_h,    // [bn][l][32] pre-scaled
    const _Float16* __restrict__ vt_h,   // [bn][kt][2048] tile-packed
    const float* __restrict__ emb_h,     // [127][32] f32
    const float* __restrict__ emb_w,     // [127][32] f32
    float* __restrict__ out)
{
    __shared__ __align__(16) char smem[33792];   // R [64][132] f32 | merge

    const int bi   = blockIdx.x;
    const int bn   = bi & 7;             // XCD swizzle
    const int w1   = bi >> 3;            // 0..63
    const int tid  = threadIdx.x;
    const int wv   = tid >> 6;           // 0..7
    const int qwv  = wv & 3;             // q-group (also R row-tile)
    const int kh   = wv >> 2;            // key half (also R col-tile group)
    const int lane = tid & 63;
    const int l16  = lane & 15;
    const int quad = lane >> 4;
    const int q0   = qwv * 16;

    float* Rl = (float*)smem;            // [h1][j] stride 132

    // ---- Q fragment: rows q0+l16, elems quad*8.. (A of R-GEMM, B of QK) ----
    const half8 aq = *(const half8*)(q_h +
        (((size_t)bn * L_ + (q0 + l16) * 64 + w1) * 32 + quad * 8));

    const _Float16* Kbase = k_h  + (size_t)bn * L_ * 32;
    const _Float16* Vtile = vt_h + (size_t)bn * 131072;
    const int lo = lane * 8;
    const int kt0 = kh * 32, ktend = kt0 + 32;

    // ---- issue first K tile load early ----
    half8 kf[4];
    #pragma unroll
    for (int sub = 0; sub < 4; sub++)
        kf[sub] = *(const half8*)(Kbase + (size_t)(kt0 * 64 + sub * 16 + l16) * 32 + quad * 8);

    // ---- qw^T C-init via Toeplitz MFMA (-FIXED_M folded in) ----
    f32x4 qwT[4];
    #pragma unroll
    for (int sub = 0; sub < 4; sub++) {
        const float* ew = emb_w + (size_t)(sub * 16 + l16 - w1 + 63) * 32 + quad * 8;
        const float4 e0 = *(const float4*)ew;
        const float4 e1 = *(const float4*)(ew + 4);
        union { uint4v u; half8 h; } ua;
        ua.u[0] = pack2u(e0.x * LOG2E, e0.y * LOG2E);
        ua.u[1] = pack2u(e0.z * LOG2E, e0.w * LOG2E);
        ua.u[2] = pack2u(e1.x * LOG2E, e1.y * LOG2E);
        ua.u[3] = pack2u(e1.z * LOG2E, e1.w * LOG2E);
        f32x4 z = {-FIXED_M, -FIXED_M, -FIXED_M, -FIXED_M};
        qwT[sub] = __builtin_amdgcn_mfma_f32_16x16x32_f16(ua.h, aq, z, 0, 0, 0);
    }

    // ---- R-GEMM: this wave computes tiles (ht=qwv, jt=kh*4..+4) ----
    #pragma unroll
    for (int ji = 0; ji < 4; ji++) {
        const int jt = kh * 4 + ji;
        int j = jt * 16 + l16; if (j > 126) j = 126;     // guard OOB row
        const float* eh = emb_h + (size_t)j * 32 + quad * 8;
        const float4 e0 = *(const float4*)eh;
        const float4 e1 = *(const float4*)(eh + 4);
        union { uint4v u; half8 h; } ub;
        ub.u[0] = pack2u(e0.x * LOG2E, e0.y * LOG2E);
        ub.u[1] = pack2u(e0.z * LOG2E, e0.w * LOG2E);
        ub.u[2] = pack2u(e1.x * LOG2E, e1.y * LOG2E);
        ub.u[3] = pack2u(e1.z * LOG2E, e1.w * LOG2E);
        f32x4 z = {0.f, 0.f, 0.f, 0.f};
        const f32x4 C = __builtin_amdgcn_mfma_f32_16x16x32_f16(aq, ub.h, z, 0, 0, 0);
        #pragma unroll
        for (int r = 0; r < 4; r++)        // row=h1 (q0+quad*4+r), col=j
            Rl[(q0 + quad * 4 + r) * 132 + jt * 16 + l16] = C[r];
    }
    __syncthreads();    // R ready

    // ---- pipeline prologue: S = QK(kt0); kf <- K(kt0+1) ----
    f32x4 S0 = __builtin_amdgcn_mfma_f32_16x16x32_f16(kf[0], aq, qwT[0], 0, 0, 0);
    f32x4 S1 = __builtin_amdgcn_mfma_f32_16x16x32_f16(kf[1], aq, qwT[1], 0, 0, 0);
    f32x4 S2 = __builtin_amdgcn_mfma_f32_16x16x32_f16(kf[2], aq, qwT[2], 0, 0, 0);
    f32x4 S3 = __builtin_amdgcn_mfma_f32_16x16x32_f16(kf[3], aq, qwT[3], 0, 0, 0);
    #pragma unroll
    for (int sub = 0; sub < 4; sub++)
        kf[sub] = *(const half8*)(Kbase + (size_t)((kt0 + 1) * 64 + sub * 16 + l16) * 32 + quad * 8);

    f32x4 O0 = {0.f, 0.f, 0.f, 0.f}, O1 = {0.f, 0.f, 0.f, 0.f};
    float l0 = 0.f, l1 = 0.f;
    const float* qh_ptr = Rl + (q0 + l16) * 132 + 63 - (q0 + l16);  // +kt per iter
#if __has_builtin(__builtin_amdgcn_fdot2)
    fp16x2 onep;
    { union { unsigned u; fp16x2 h; } uo; uo.u = pack2u(1.0f, 1.0f); onep = uo.h; }
#endif

    #pragma unroll 4
    for (int kt = kt0; kt < ktend; kt++) {
        // ---- issue QK(kt+1) on the MFMA pipe (last iter: harmless junk) ----
        f32x4 T0 = __builtin_amdgcn_mfma_f32_16x16x32_f16(kf[0], aq, qwT[0], 0, 0, 0);
        f32x4 T1 = __builtin_amdgcn_mfma_f32_16x16x32_f16(kf[1], aq, qwT[1], 0, 0, 0);
        f32x4 T2 = __builtin_amdgcn_mfma_f32_16x16x32_f16(kf[2], aq, qwT[2], 0, 0, 0);
        f32x4 T3 = __builtin_amdgcn_mfma_f32_16x16x32_f16(kf[3], aq, qwT[3], 0, 0, 0);

        // ---- prefetch K(kt+2) (lands in adjacent ws when OOB; never used) ----
        #pragma unroll
        for (int sub = 0; sub < 4; sub++)
            kf[sub] = *(const half8*)(Kbase + (size_t)((kt + 2) * 64 + sub * 16 + l16) * 32 + quad * 8);

        // ---- V(kt): single 1KB-segment lane-contiguous half8 each ----
        const _Float16* tb = Vtile + kt * 2048;
        const half8 va00 = *(const half8*)(tb + lo);
        const half8 va10 = *(const half8*)(tb + 512 + lo);
        const half8 va01 = *(const half8*)(tb + 1024 + lo);
        const half8 va11 = *(const half8*)(tb + 1536 + lo);

        // ---- qh from LDS R (conflict-free; broadcast over quads) ----
        const float qh_cur = qh_ptr[kt];

        // ---- exp/pack tile kt from S (one-iteration-old: no MFMA stall) ----
        union { uint4v u; half8 h; } pb0, pb1;
        {
            const float a0 = fexp2(S0[0] + qh_cur), a1 = fexp2(S0[1] + qh_cur);
            const float a2 = fexp2(S0[2] + qh_cur), a3 = fexp2(S0[3] + qh_cur);
            const float b0 = fexp2(S1[0] + qh_cur), b1 = fexp2(S1[1] + qh_cur);
            const float b2 = fexp2(S1[2] + qh_cur), b3 = fexp2(S1[3] + qh_cur);
            pb0.u[0] = pack2u(a0, a1); pb0.u[1] = pack2u(a2, a3);
            pb0.u[2] = pack2u(b0, b1); pb0.u[3] = pack2u(b2, b3);
#if __has_builtin(__builtin_amdgcn_fdot2)
            union { unsigned u; fp16x2 h; } c0, c1, c2, c3;
            c0.u = pb0.u[0]; c1.u = pb0.u[1]; c2.u = pb0.u[2]; c3.u = pb0.u[3];
            l0 = __builtin_amdgcn_fdot2(c0.h, onep, l0, false);
            l0 = __builtin_amdgcn_fdot2(c1.h, onep, l0, false);
            l0 = __builtin_amdgcn_fdot2(c2.h, onep, l0, false);
            l0 = __builtin_amdgcn_fdot2(c3.h, onep, l0, false);
#else
            l0 += ((a0 + a1) + (a2 + a3)) + ((b0 + b1) + (b2 + b3));
#endif
        }
        {
            const float a0 = fexp2(S2[0] + qh_cur), a1 = fexp2(S2[1] + qh_cur);
            const float a2 = fexp2(S2[2] + qh_cur), a3 = fexp2(S2[3] + qh_cur);
            const float b0 = fexp2(S3[0] + qh_cur), b1 = fexp2(S3[1] + qh_cur);
            const float b2 = fexp2(S3[2] + qh_cur), b3 = fexp2(S3[3] + qh_cur);
            pb1.u[0] = pack2u(a0, a1); pb1.u[1] = pack2u(a2, a3);
            pb1.u[2] = pack2u(b0, b1); pb1.u[3] = pack2u(b2, b3);
#if __has_builtin(__builtin_amdgcn_fdot2)
            union { unsigned u; fp16x2 h; } c0, c1, c2, c3;
            c0.u = pb1.u[0]; c1.u = pb1.u[1]; c2.u = pb1.u[2]; c3.u = pb1.u[3];
            l1 = __builtin_amdgcn_fdot2(c0.h, onep, l1, false);
            l1 = __builtin_amdgcn_fdot2(c1.h, onep, l1, false);
            l1 = __builtin_amdgcn_fdot2(c2.h, onep, l1, false);
            l1 = __builtin_amdgcn_fdot2(c3.h, onep, l1, false);
#else
            l1 += ((a0 + a1) + (a2 + a3)) + ((b0 + b1) + (b2 + b3));
#endif
        }

        // ---- PV(kt) ----
        O0 = __builtin_amdgcn_mfma_f32_16x16x32_f16(va00, pb0.h, O0, 0, 0, 0);
        O0 = __builtin_amdgcn_mfma_f32_16x16x32_f16(va01, pb1.h, O0, 0, 0, 0);
        O1 = __builtin_amdgcn_mfma_f32_16x16x32_f16(va10, pb0.h, O1, 0, 0, 0);
        O1 = __builtin_amdgcn_mfma_f32_16x16x32_f16(va11, pb1.h, O1, 0, 0, 0);

        // ---- rotate score regs ----
        S0 = T0; S1 = T1; S2 = T2; S3 = T3;
    }

    // ---- reduce l over quads (per-lane q = l16) ----
    float l = l0 + l1;
    l += __shfl_xor(l, 16);
    l += __shfl_xor(l, 32);

    // ---- merge overlay (R dead after barrier) ----
    __syncthreads();
    float (*mO)[32][17] = (float(*)[32][17])smem;     // [wave][d][q16]
    float* mL = (float*)(smem + 17408);               // [wave][16]
    #pragma unroll
    for (int r = 0; r < 4; r++) {
        mO[wv][quad * 4 + r][l16]      = O0[r];
        mO[wv][16 + quad * 4 + r][l16] = O1[r];
    }
    if (quad == 0) mL[wv * 16 + l16] = l;
    __syncthreads();

    // thread t: q = t>>3 (0..63), dg = t&7 (4 channels) -> coalesced float4
    const int q  = tid >> 3;
    const int dg = tid & 7;
    const int qg = q >> 4, ql = q & 15;
    const float denom = mL[qg * 16 + ql] + mL[(qg + 4) * 16 + ql];
    const float inv = 1.0f / denom;
    float4 o;
    o.x = (mO[qg][dg * 4 + 0][ql] + mO[qg + 4][dg * 4 + 0][ql]) * inv;
    o.y = (mO[qg][dg * 4 + 1][ql] + mO[qg + 4][dg * 4 + 1][ql]) * inv;
    o.z = (mO[qg][dg * 4 + 2][ql] + mO[qg + 4][dg * 4 + 2][ql]) * inv;
    o.w = (mO[qg][dg * 4 + 3][ql] + mO[qg + 4][dg * 4 + 3][ql]) * inv;
    const int head = bn & 3, bb = bn >> 2;
    *(float4*)&out[(((size_t)bb * 64 + q) * 64 + w1) * 128 + head * 32 + dg * 4] = o;
}

// ---------------------------------------------------------------------------
extern "C" void kernel_launch(void* const* d_in, const int* in_sizes, int n_in,
                              void* d_out, int out_size, void* d_ws, size_t ws_size,
                              hipStream_t stream) {
    const float* x     = (const float*)d_in[0];   // [2,64,64,128]
    const float* w_qkv = (const float*)d_in[1];   // [128,384]
    const float* emb_h = (const float*)d_in[2];   // [127,32]
    const float* emb_w = (const float*)d_in[3];   // [127,32]
    float* out = (float*)d_out;

    // workspace: q_h/k_h 1M half each | vt_h 1M half tiled (vt_h also guards
    // the unconditional K prefetch up to 2 tiles past k_h's end)
    _Float16* q_h  = (_Float16*)d_ws;
    _Float16* k_h  = q_h + (size_t)BN_ * L_ * KD;
    _Float16* vt_h = k_h + (size_t)BN_ * L_ * KD;

    qkv_gemm<<<768, 256, 0, stream>>>(x, w_qkv, q_h, k_h, vt_h);
    attn_mfma<<<512, 512, 0, stream>>>(q_h, k_h, vt_h, emb_h, emb_w, out);
}

// Round 16
// 122.872 us; speedup vs baseline: 1.4694x; 1.0604x over previous
//
#include <hip/hip_runtime.h>
#include <hip/hip_bf16.h>
#include <math.h>

// Problem constants (fixed by setup_inputs)
#define B_  2
#define NH  4
#define HH  64
#define WW  64
#define KD  32
#define L_  4096            // HH*WW
#define BN_ 8               // B_*NH
#define LOG2E 1.4426950408889634f
#define KSCALE (0.17677669529663687f * 1.4426950408889634f)  // log2e/sqrt(32)
#define FIXED_M 10.0f   // log2-domain fixed softmax shift (shift-invariant =>
                        // exact); scores max ~3, p=2^(s-10) f16-safe to s>26.

typedef float    f32x4  __attribute__((ext_vector_type(4), may_alias));
typedef _Float16 half8  __attribute__((ext_vector_type(8), may_alias));
typedef _Float16 half4  __attribute__((ext_vector_type(4), may_alias));
typedef __fp16   fp16x2 __attribute__((ext_vector_type(2)));
typedef unsigned uint4v __attribute__((ext_vector_type(4)));

__device__ __forceinline__ float fexp2(float x) {
#if __has_builtin(__builtin_amdgcn_exp2f)
    return __builtin_amdgcn_exp2f(x);
#else
    return __expf(x * 0.69314718056f);
#endif
}

__device__ __forceinline__ unsigned pack2u(float a, float b) {
    fp16x2 t = __builtin_amdgcn_cvt_pkrtz(a, b);   // v_cvt_pkrtz_f16_f32
    union { fp16x2 i; unsigned o; } u;
    u.i = t;
    return u.o;
}

// ---------------------------------------------------------------------------
// Kernel A: qkv = x @ w_qkv (M=8192,K=128,N=384), f16 MFMA, single LDS pass
// (K=128). Outputs: q_h/k_h [bn][l][32] (k pre-scaled by log2e/sqrt32), and
// TILE-PACKED V (R13 layout): attention PV A-operand = single lane-contiguous
// 1KB-segment half8.
// ---------------------------------------------------------------------------
__global__ __launch_bounds__(256) void qkv_gemm(const float* __restrict__ x,
                                                const float* __restrict__ w,
                                                _Float16* __restrict__ q_h,
                                                _Float16* __restrict__ k_h,
                                                _Float16* __restrict__ vt_h) {
    __shared__ __align__(16) char smem[34816];
    _Float16* xs  = (_Float16*)smem;            // [64][136]
    _Float16* wsT = (_Float16*)(smem + 17408);  // [64][136] transposed w

    const int mt = blockIdx.x % 128;
    const int nt = blockIdx.x / 128;
    const int m0 = mt * 64, n0 = nt * 64;
    const int tid = threadIdx.x;
    const int wv = tid >> 6, lane = tid & 63;
    const int l16 = lane & 15, quad = lane >> 4;

    #pragma unroll
    for (int i = 0; i < 8; i++) {
        const int idx = i * 256 + tid;
        const int row = idx >> 5, c4 = (idx & 31) * 4;
        const float4 v = *(const float4*)&x[(size_t)(m0 + row) * 128 + c4];
        half4 h;
        h[0] = (_Float16)v.x; h[1] = (_Float16)v.y;
        h[2] = (_Float16)v.z; h[3] = (_Float16)v.w;
        *(half4*)&xs[row * 136 + c4] = h;
    }
    #pragma unroll
    for (int i = 0; i < 8; i++) {
        const int idx = i * 256 + tid;
        const int k = idx >> 4, c4 = (idx & 15) * 4;
        const float4 v = *(const float4*)&w[(size_t)k * 384 + n0 + c4];
        wsT[(c4 + 0) * 136 + k] = (_Float16)v.x;
        wsT[(c4 + 1) * 136 + k] = (_Float16)v.y;
        wsT[(c4 + 2) * 136 + k] = (_Float16)v.z;
        wsT[(c4 + 3) * 136 + k] = (_Float16)v.w;
    }
    __syncthreads();

    f32x4 acc[4] = {{0.f,0.f,0.f,0.f},{0.f,0.f,0.f,0.f},
                    {0.f,0.f,0.f,0.f},{0.f,0.f,0.f,0.f}};
    half8 af[4];
    #pragma unroll
    for (int kc = 0; kc < 4; kc++)
        af[kc] = *(const half8*)&xs[(wv * 16 + l16) * 136 + kc * 32 + quad * 8];
    #pragma unroll
    for (int ns = 0; ns < 4; ns++)
        #pragma unroll
        for (int kc = 0; kc < 4; kc++) {
            const half8 bf = *(const half8*)&wsT[(ns * 16 + l16) * 136 + kc * 32 + quad * 8];
            acc[ns] = __builtin_amdgcn_mfma_f32_16x16x32_f16(af[kc], bf, acc[ns], 0, 0, 0);
        }

    const int which = n0 >> 7;                 // 0=q, 1=k, 2=v
    const int nc = n0 & 127;
    const int b = m0 >> 12;
    if (which < 2) {
        _Float16* dst = (which == 0) ? q_h : k_h;
        const float mult = (which == 1) ? KSCALE : 1.0f;
        #pragma unroll
        for (int ns = 0; ns < 4; ns++) {
            const int col = nc + ns * 16 + l16;
            const int bn = b * NH + (col >> 5);
            const int d = col & 31;
            #pragma unroll
            for (int r = 0; r < 4; r++) {
                const int l = (m0 & 4095) + wv * 16 + quad * 4 + r;
                dst[((size_t)bn * L_ + l) * 32 + d] = (_Float16)(acc[ns][r] * mult);
            }
        }
    } else {
        __syncthreads();                        // xs dead -> overlay img
        float* img = (float*)smem;
        #pragma unroll
        for (int ns = 0; ns < 4; ns++) {
            const int chan = ns * 16 + l16;
            const int h = chan >> 5, d = chan & 31;
            #pragma unroll
            for (int r = 0; r < 4; r++) {
                const int p = wv * 16 + quad * 4 + r;
                const int y = p >> 5, p32 = p & 31;
                const int q4 = (p32 >> 2) & 3;
                const int j = ((p32 >> 4) & 1) * 4 + (p32 & 3);
                const int fidx = h * 2048 + (y * 2 + (d >> 4)) * 512
                               + (q4 * 16 + (d & 15)) * 8 + j;
                img[fidx + (fidx >> 4)] = acc[ns][r];
            }
        }
        __syncthreads();
        const int ktg = (m0 & 4095) >> 6;
        #pragma unroll
        for (int h = 0; h < 2; h++) {
            const int head = (nc >> 5) + h;
            const int bn = b * NH + head;
            const int fbase = h * 2048 + tid * 8;
            const int sbase = fbase + (fbase >> 4);
            half8 o;
            #pragma unroll
            for (int e = 0; e < 8; e++) o[e] = (_Float16)img[sbase + e];
            *(half8*)(vt_h + (size_t)bn * 131072 + ktg * 2048 + tid * 8) = o;
        }
    }
}

// ---------------------------------------------------------------------------
// Kernel B: transposed MFMA flash attention; fixed-m softmax; tile-packed V;
// both biases fused in-block (qw^T Toeplitz C-init with -FIXED_M folded;
// qh via R-GEMM into LDS). R16: in-order loop (R15's 2-tile skew reverted:
// it regressed 58->72) + PER-WAVE RING PHASE: wave wv starts its 32-key half
// at offset {0,8,16,24,4,12,20,28} and wraps. Waves sharing a SIMD are >=4
// iterations out of phase -> their vmcnt waits no longer convoy (the
// lockstep-stall hypothesis for the ~22% issue efficiency).
// Block (bn,w1), 8 waves = 4 q-groups x 2 key-halves.
// ---------------------------------------------------------------------------
__global__ __launch_bounds__(512, 4) void attn_mfma(
    const _Float16* __restrict__ q_h,    // [bn][l][32]
    const _Float16* __restrict__ k_h,    // [bn][l][32] pre-scaled
    const _Float16* __restrict__ vt_h,   // [bn][kt][2048] tile-packed
    const float* __restrict__ emb_h,     // [127][32] f32
    const float* __restrict__ emb_w,     // [127][32] f32
    float* __restrict__ out)
{
    __shared__ __align__(16) char smem[33792];   // R [64][132] f32 | merge

    const int bi   = blockIdx.x;
    const int bn   = bi & 7;             // XCD swizzle
    const int w1   = bi >> 3;            // 0..63
    const int tid  = threadIdx.x;
    const int wv   = tid >> 6;           // 0..7
    const int qwv  = wv & 3;             // q-group (also R row-tile)
    const int kh   = wv >> 2;            // key half (also R col-tile group)
    const int lane = tid & 63;
    const int l16  = lane & 15;
    const int quad = lane >> 4;
    const int q0   = qwv * 16;

    float* Rl = (float*)smem;            // [h1][j] stride 132

    // ---- Q fragment: rows q0+l16, elems quad*8.. (A of R-GEMM, B of QK) ----
    const half8 aq = *(const half8*)(q_h +
        (((size_t)bn * L_ + (q0 + l16) * 64 + w1) * 32 + quad * 8));

    const _Float16* Kbase = k_h  + (size_t)bn * L_ * 32;
    const _Float16* Vtile = vt_h + (size_t)bn * 131072;
    const int lo = lane * 8;
    const int kt0 = kh * 32;
    const int phase = ((wv & 3) << 3) | ((wv >> 2) << 2);  // 0,8,16,24,4,12,20,28

    // ---- issue first K tile load early (ring start) ----
    int kt = kt0 + phase;
    half8 kf[4];
    #pragma unroll
    for (int sub = 0; sub < 4; sub++)
        kf[sub] = *(const half8*)(Kbase + (size_t)(kt * 64 + sub * 16 + l16) * 32 + quad * 8);

    // ---- qw^T C-init via Toeplitz MFMA (-FIXED_M folded in) ----
    f32x4 qwT[4];
    #pragma unroll
    for (int sub = 0; sub < 4; sub++) {
        const float* ew = emb_w + (size_t)(sub * 16 + l16 - w1 + 63) * 32 + quad * 8;
        const float4 e0 = *(const float4*)ew;
        const float4 e1 = *(const float4*)(ew + 4);
        union { uint4v u; half8 h; } ua;
        ua.u[0] = pack2u(e0.x * LOG2E, e0.y * LOG2E);
        ua.u[1] = pack2u(e0.z * LOG2E, e0.w * LOG2E);
        ua.u[2] = pack2u(e1.x * LOG2E, e1.y * LOG2E);
        ua.u[3] = pack2u(e1.z * LOG2E, e1.w * LOG2E);
        f32x4 z = {-FIXED_M, -FIXED_M, -FIXED_M, -FIXED_M};
        qwT[sub] = __builtin_amdgcn_mfma_f32_16x16x32_f16(ua.h, aq, z, 0, 0, 0);
    }

    // ---- R-GEMM: this wave computes tiles (ht=qwv, jt=kh*4..+4) ----
    #pragma unroll
    for (int ji = 0; ji < 4; ji++) {
        const int jt = kh * 4 + ji;
        int j = jt * 16 + l16; if (j > 126) j = 126;     // guard OOB row
        const float* eh = emb_h + (size_t)j * 32 + quad * 8;
        const float4 e0 = *(const float4*)eh;
        const float4 e1 = *(const float4*)(eh + 4);
        union { uint4v u; half8 h; } ub;
        ub.u[0] = pack2u(e0.x * LOG2E, e0.y * LOG2E);
        ub.u[1] = pack2u(e0.z * LOG2E, e0.w * LOG2E);
        ub.u[2] = pack2u(e1.x * LOG2E, e1.y * LOG2E);
        ub.u[3] = pack2u(e1.z * LOG2E, e1.w * LOG2E);
        f32x4 z = {0.f, 0.f, 0.f, 0.f};
        const f32x4 C = __builtin_amdgcn_mfma_f32_16x16x32_f16(aq, ub.h, z, 0, 0, 0);
        #pragma unroll
        for (int r = 0; r < 4; r++)        // row=h1 (q0+quad*4+r), col=j
            Rl[(q0 + quad * 4 + r) * 132 + jt * 16 + l16] = C[r];
    }
    __syncthreads();    // R ready

    f32x4 O0 = {0.f, 0.f, 0.f, 0.f}, O1 = {0.f, 0.f, 0.f, 0.f};
    float l0 = 0.f, l1 = 0.f;
    const float* qh_ptr = Rl + (q0 + l16) * 132 + 63 - (q0 + l16);  // +kt per read
#if __has_builtin(__builtin_amdgcn_fdot2)
    fp16x2 onep;
    { union { unsigned u; fp16x2 h; } uo; uo.u = pack2u(1.0f, 1.0f); onep = uo.h; }
#endif

    #pragma unroll 4
    for (int i = 0; i < 32; i++) {
        // ---- V(kt): single 1KB-segment lane-contiguous half8 each ----
        const _Float16* tb = Vtile + kt * 2048;
        const half8 va00 = *(const half8*)(tb + lo);
        const half8 va10 = *(const half8*)(tb + 512 + lo);
        const half8 va01 = *(const half8*)(tb + 1024 + lo);
        const half8 va11 = *(const half8*)(tb + 1536 + lo);

        // ---- QK^T transposed: S^T[key][q], qw-FIXED_M as C-init ----
        const f32x4 S0 = __builtin_amdgcn_mfma_f32_16x16x32_f16(kf[0], aq, qwT[0], 0, 0, 0);
        const f32x4 S1 = __builtin_amdgcn_mfma_f32_16x16x32_f16(kf[1], aq, qwT[1], 0, 0, 0);
        const f32x4 S2 = __builtin_amdgcn_mfma_f32_16x16x32_f16(kf[2], aq, qwT[2], 0, 0, 0);
        const f32x4 S3 = __builtin_amdgcn_mfma_f32_16x16x32_f16(kf[3], aq, qwT[3], 0, 0, 0);

        // ---- qh from LDS R (conflict-free; broadcast over quads) ----
        const float qh_cur = qh_ptr[kt];

        // ---- prefetch next ring K tile (always in range) ----
        const int ktn = kt0 + (((kt - kt0) + 1) & 31);
        #pragma unroll
        for (int sub = 0; sub < 4; sub++)
            kf[sub] = *(const half8*)(Kbase + (size_t)(ktn * 64 + sub * 16 + l16) * 32 + quad * 8);

        // ---- fixed-m softmax: p = 2^(S + qh); u32-concat pack ----
        union { uint4v u; half8 h; } pb0, pb1;
        {
            const float a0 = fexp2(S0[0] + qh_cur), a1 = fexp2(S0[1] + qh_cur);
            const float a2 = fexp2(S0[2] + qh_cur), a3 = fexp2(S0[3] + qh_cur);
            const float b0 = fexp2(S1[0] + qh_cur), b1 = fexp2(S1[1] + qh_cur);
            const float b2 = fexp2(S1[2] + qh_cur), b3 = fexp2(S1[3] + qh_cur);
            pb0.u[0] = pack2u(a0, a1); pb0.u[1] = pack2u(a2, a3);
            pb0.u[2] = pack2u(b0, b1); pb0.u[3] = pack2u(b2, b3);
#if __has_builtin(__builtin_amdgcn_fdot2)
            union { unsigned u; fp16x2 h; } c0, c1, c2, c3;
            c0.u = pb0.u[0]; c1.u = pb0.u[1]; c2.u = pb0.u[2]; c3.u = pb0.u[3];
            l0 = __builtin_amdgcn_fdot2(c0.h, onep, l0, false);
            l0 = __builtin_amdgcn_fdot2(c1.h, onep, l0, false);
            l0 = __builtin_amdgcn_fdot2(c2.h, onep, l0, false);
            l0 = __builtin_amdgcn_fdot2(c3.h, onep, l0, false);
#else
            l0 += ((a0 + a1) + (a2 + a3)) + ((b0 + b1) + (b2 + b3));
#endif
        }
        {
            const float a0 = fexp2(S2[0] + qh_cur), a1 = fexp2(S2[1] + qh_cur);
            const float a2 = fexp2(S2[2] + qh_cur), a3 = fexp2(S2[3] + qh_cur);
            const float b0 = fexp2(S3[0] + qh_cur), b1 = fexp2(S3[1] + qh_cur);
            const float b2 = fexp2(S3[2] + qh_cur), b3 = fexp2(S3[3] + qh_cur);
            pb1.u[0] = pack2u(a0, a1); pb1.u[1] = pack2u(a2, a3);
            pb1.u[2] = pack2u(b0, b1); pb1.u[3] = pack2u(b2, b3);
#if __has_builtin(__builtin_amdgcn_fdot2)
            union { unsigned u; fp16x2 h; } c0, c1, c2, c3;
            c0.u = pb1.u[0]; c1.u = pb1.u[1]; c2.u = pb1.u[2]; c3.u = pb1.u[3];
            l1 = __builtin_amdgcn_fdot2(c0.h, onep, l1, false);
            l1 = __builtin_amdgcn_fdot2(c1.h, onep, l1, false);
            l1 = __builtin_amdgcn_fdot2(c2.h, onep, l1, false);
            l1 = __builtin_amdgcn_fdot2(c3.h, onep, l1, false);
#else
            l1 += ((a0 + a1) + (a2 + a3)) + ((b0 + b1) + (b2 + b3));
#endif
        }

        // ---- PV(kt) ----
        O0 = __builtin_amdgcn_mfma_f32_16x16x32_f16(va00, pb0.h, O0, 0, 0, 0);
        O0 = __builtin_amdgcn_mfma_f32_16x16x32_f16(va01, pb1.h, O0, 0, 0, 0);
        O1 = __builtin_amdgcn_mfma_f32_16x16x32_f16(va10, pb0.h, O1, 0, 0, 0);
        O1 = __builtin_amdgcn_mfma_f32_16x16x32_f16(va11, pb1.h, O1, 0, 0, 0);

        kt = ktn;
    }

    // ---- reduce l over quads (per-lane q = l16) ----
    float l = l0 + l1;
    l += __shfl_xor(l, 16);
    l += __shfl_xor(l, 32);

    // ---- merge overlay (R dead after barrier) ----
    __syncthreads();
    float (*mO)[32][17] = (float(*)[32][17])smem;     // [wave][d][q16]
    float* mL = (float*)(smem + 17408);               // [wave][16]
    #pragma unroll
    for (int r = 0; r < 4; r++) {
        mO[wv][quad * 4 + r][l16]      = O0[r];
        mO[wv][16 + quad * 4 + r][l16] = O1[r];
    }
    if (quad == 0) mL[wv * 16 + l16] = l;
    __syncthreads();

    // thread t: q = t>>3 (0..63), dg = t&7 (4 channels) -> coalesced float4
    const int q  = tid >> 3;
    const int dg = tid & 7;
    const int qg = q >> 4, ql = q & 15;
    const float denom = mL[qg * 16 + ql] + mL[(qg + 4) * 16 + ql];
    const float inv = 1.0f / denom;
    float4 o;
    o.x = (mO[qg][dg * 4 + 0][ql] + mO[qg + 4][dg * 4 + 0][ql]) * inv;
    o.y = (mO[qg][dg * 4 + 1][ql] + mO[qg + 4][dg * 4 + 1][ql]) * inv;
    o.z = (mO[qg][dg * 4 + 2][ql] + mO[qg + 4][dg * 4 + 2][ql]) * inv;
    o.w = (mO[qg][dg * 4 + 3][ql] + mO[qg + 4][dg * 4 + 3][ql]) * inv;
    const int head = bn & 3, bb = bn >> 2;
    *(float4*)&out[(((size_t)bb * 64 + q) * 64 + w1) * 128 + head * 32 + dg * 4] = o;
}

// ---------------------------------------------------------------------------
extern "C" void kernel_launch(void* const* d_in, const int* in_sizes, int n_in,
                              void* d_out, int out_size, void* d_ws, size_t ws_size,
                              hipStream_t stream) {
    const float* x     = (const float*)d_in[0];   // [2,64,64,128]
    const float* w_qkv = (const float*)d_in[1];   // [128,384]
    const float* emb_h = (const float*)d_in[2];   // [127,32]
    const float* emb_w = (const float*)d_in[3];   // [127,32]
    float* out = (float*)d_out;

    // workspace: q_h/k_h 1M half each | vt_h 1M half tiled
    _Float16* q_h  = (_Float16*)d_ws;
    _Float16* k_h  = q_h + (size_t)BN_ * L_ * KD;
    _Float16* vt_h = k_h + (size_t)BN_ * L_ * KD;

    qkv_gemm<<<768, 256, 0, stream>>>(x, w_qkv, q_h, k_h, vt_h);
    attn_mfma<<<512, 512, 0, stream>>>(q_h, k_h, vt_h, emb_h, emb_w, out);
}